// Round 4
// baseline (364.295 us; speedup 1.0000x reference)
//
#include <hip/hip_runtime.h>
#include <math.h>

#define NF 32
#define NN 4096
#define ND 64
#define NK 512
#define KSPLIT 4
#define KCH (NK / KSPLIT)   // 128 codewords per z-slice

// loss = q_latent + 0.25 * e_latent = 1.25 * mean((q - x)^2)
#define LOSS_SCALE (1.25f / (float)(NF * NN * ND))

typedef float v4f __attribute__((ext_vector_type(4)));

// ---------------------------------------------------------------------------
// prep1: transpose wt[f][k][d] = w[f][d][k]; init keys; zero loss.
// thread per (f, k, d4): 262144 threads = 1024 blocks.
// ---------------------------------------------------------------------------
__global__ __launch_bounds__(256)
void vq_prep1(const float* __restrict__ w, float* __restrict__ wt,
              unsigned long long* __restrict__ keys,
              float* __restrict__ loss_slot) {
    const int gid = blockIdx.x * 256 + threadIdx.x;   // [0, NF*NK*16)
    if (gid == 0) *loss_slot = 0.0f;
    if (gid < NF * NN) keys[gid] = 0xFFFFFFFFFFFFFFFFULL;

    const int d4 = gid & 15;
    const int k  = (gid >> 4) & (NK - 1);
    const int f  = gid >> 13;
    const float* __restrict__ wf = w + (size_t)f * ND * NK;
    float4 v;
    v.x = wf[(4 * d4 + 0) * NK + k];
    v.y = wf[(4 * d4 + 1) * NK + k];
    v.z = wf[(4 * d4 + 2) * NK + k];
    v.w = wf[(4 * d4 + 3) * NK + k];
    *(float4*)(wt + (((size_t)f * NK + k) * ND) + 4 * d4) = v;
}

// ---------------------------------------------------------------------------
// prep2: w2h[f][k] = 0.5*||w_k||^2 from contiguous wt rows.
// thread per (f,k): 16384 threads = 64 blocks.
// ---------------------------------------------------------------------------
__global__ __launch_bounds__(256)
void vq_prep2(const float* __restrict__ wt, float* __restrict__ w2h) {
    const int gid = blockIdx.x * 256 + threadIdx.x;   // [0, NF*NK)
    const float* __restrict__ r = wt + (size_t)gid * ND;
    float s = 0.0f;
#pragma unroll
    for (int d4 = 0; d4 < ND / 4; ++d4) {
        float4 v = *(const float4*)(r + 4 * d4);
        s = fmaf(v.x, v.x, s);
        s = fmaf(v.y, v.y, s);
        s = fmaf(v.z, v.z, s);
        s = fmaf(v.w, v.w, s);
    }
    w2h[gid] = 0.5f * s;
}

// ---------------------------------------------------------------------------
// argmin over a K-slice. score_k = 0.5*||w_k||^2 - x.w_k. Winner published
// via atomicMin on key = (monotone_enc(score) << 32) | k  -> exact global
// argmin, lowest-index tie-break. x row held in VGPRs via inline-asm loads
// (un-rematerializable). w loads are wave-uniform -> scalar SMEM broadcast.
// grid: (NN/256, NF, KSPLIT) = 2048 blocks.
// ---------------------------------------------------------------------------

#define XD(i) xv[(i) >> 2][(i) & 3]

#define LOADC(Bf, dc) do {                                      \
    Bf[0] = *(const v4f*)(pw + 0 * ND + (dc));                  \
    Bf[1] = *(const v4f*)(pw + 0 * ND + (dc) + 4);              \
    Bf[2] = *(const v4f*)(pw + 1 * ND + (dc));                  \
    Bf[3] = *(const v4f*)(pw + 1 * ND + (dc) + 4);              \
    Bf[4] = *(const v4f*)(pw + 2 * ND + (dc));                  \
    Bf[5] = *(const v4f*)(pw + 2 * ND + (dc) + 4);              \
    Bf[6] = *(const v4f*)(pw + 3 * ND + (dc));                  \
    Bf[7] = *(const v4f*)(pw + 3 * ND + (dc) + 4);              \
} while (0)

#define FMA8(t, q0, q1, dc) do {                                \
    t = fmaf(-XD((dc) + 0), q0[0], t);                          \
    t = fmaf(-XD((dc) + 1), q0[1], t);                          \
    t = fmaf(-XD((dc) + 2), q0[2], t);                          \
    t = fmaf(-XD((dc) + 3), q0[3], t);                          \
    t = fmaf(-XD((dc) + 4), q1[0], t);                          \
    t = fmaf(-XD((dc) + 5), q1[1], t);                          \
    t = fmaf(-XD((dc) + 6), q1[2], t);                          \
    t = fmaf(-XD((dc) + 7), q1[3], t);                          \
} while (0)

#define FMAC(Bf, dc) do {                                       \
    FMA8(t0, Bf[0], Bf[1], dc);                                 \
    FMA8(t1, Bf[2], Bf[3], dc);                                 \
    FMA8(t2, Bf[4], Bf[5], dc);                                 \
    FMA8(t3, Bf[6], Bf[7], dc);                                 \
} while (0)

__global__ __launch_bounds__(256, 4)
void vq_argmin(const float* __restrict__ x_in, const float* __restrict__ wt,
               const float* __restrict__ w2h,
               unsigned long long* __restrict__ keys) {
    const int f  = blockIdx.y;
    const int n  = blockIdx.x * 256 + threadIdx.x;
    const int ks = blockIdx.z * KCH;

    const float* __restrict__ wtf = wt + (size_t)f * NK * ND;
    const float* __restrict__ xr  = x_in + ((size_t)f * NN + n) * ND;

    __shared__ float w2s[KCH];
    if (threadIdx.x < KCH) w2s[threadIdx.x] = w2h[f * NK + ks + threadIdx.x];
    __syncthreads();

    // ---- x row into VGPRs via asm loads: cannot be rematerialized ----
    v4f xv[16];
    asm volatile("global_load_dwordx4 %0, %1, off offset:0"   : "=v"(xv[0])  : "v"(xr));
    asm volatile("global_load_dwordx4 %0, %1, off offset:16"  : "=v"(xv[1])  : "v"(xr));
    asm volatile("global_load_dwordx4 %0, %1, off offset:32"  : "=v"(xv[2])  : "v"(xr));
    asm volatile("global_load_dwordx4 %0, %1, off offset:48"  : "=v"(xv[3])  : "v"(xr));
    asm volatile("global_load_dwordx4 %0, %1, off offset:64"  : "=v"(xv[4])  : "v"(xr));
    asm volatile("global_load_dwordx4 %0, %1, off offset:80"  : "=v"(xv[5])  : "v"(xr));
    asm volatile("global_load_dwordx4 %0, %1, off offset:96"  : "=v"(xv[6])  : "v"(xr));
    asm volatile("global_load_dwordx4 %0, %1, off offset:112" : "=v"(xv[7])  : "v"(xr));
    asm volatile("global_load_dwordx4 %0, %1, off offset:128" : "=v"(xv[8])  : "v"(xr));
    asm volatile("global_load_dwordx4 %0, %1, off offset:144" : "=v"(xv[9])  : "v"(xr));
    asm volatile("global_load_dwordx4 %0, %1, off offset:160" : "=v"(xv[10]) : "v"(xr));
    asm volatile("global_load_dwordx4 %0, %1, off offset:176" : "=v"(xv[11]) : "v"(xr));
    asm volatile("global_load_dwordx4 %0, %1, off offset:192" : "=v"(xv[12]) : "v"(xr));
    asm volatile("global_load_dwordx4 %0, %1, off offset:208" : "=v"(xv[13]) : "v"(xr));
    asm volatile("global_load_dwordx4 %0, %1, off offset:224" : "=v"(xv[14]) : "v"(xr));
    asm volatile("global_load_dwordx4 %0, %1, off offset:240" : "=v"(xv[15]) : "v"(xr));
    asm volatile("s_waitcnt vmcnt(0)" ::: "memory");
#pragma unroll
    for (int i = 0; i < 16; ++i) asm volatile("" : "+v"(xv[i]));

    float best = INFINITY;
    int bidx = ks;

    for (int kk = 0; kk < KCH; kk += 4) {
        const int k0 = ks + kk;
        const float* __restrict__ pw = wtf + (size_t)k0 * ND;  // 1KB contiguous
        float t0 = w2s[kk + 0];
        float t1 = w2s[kk + 1];
        float t2 = w2s[kk + 2];
        float t3 = w2s[kk + 3];

        v4f A[8], B[8];
        LOADC(A, 0);
        LOADC(B, 8);
        FMAC(A, 0);
        LOADC(A, 16);
        FMAC(B, 8);
        LOADC(B, 24);
        FMAC(A, 16);
        LOADC(A, 32);
        FMAC(B, 24);
        LOADC(B, 40);
        FMAC(A, 32);
        LOADC(A, 48);
        FMAC(B, 40);
        LOADC(B, 56);
        FMAC(A, 48);
        FMAC(B, 56);

        if (t0 < best) { best = t0; bidx = k0 + 0; }
        if (t1 < best) { best = t1; bidx = k0 + 1; }
        if (t2 < best) { best = t2; bidx = k0 + 2; }
        if (t3 < best) { best = t3; bidx = k0 + 3; }
    }

    // monotone float->uint encoding; key = enc << 32 | k
    unsigned int u = __float_as_uint(best);
    u ^= (unsigned int)(((int)u >> 31)) | 0x80000000u;
    const unsigned long long key =
        ((unsigned long long)u << 32) | (unsigned long long)bidx;
    atomicMin(&keys[(size_t)f * NN + n], key);
}

// ---------------------------------------------------------------------------
// gather: 4 threads per row (16 elems each). Consecutive lanes cover
// contiguous memory (wave = 16 rows = 4KB). 524288 threads = 2048 blocks.
// ---------------------------------------------------------------------------
__global__ __launch_bounds__(256)
void vq_gather(const float* __restrict__ x_in, const float* __restrict__ wt,
               const unsigned long long* __restrict__ keys,
               float* __restrict__ out) {
    const int gid = blockIdx.x * 256 + threadIdx.x;   // [0, NF*NN*4)
    const int row = gid >> 2;
    const int c   = (gid & 3) * 16;                   // d-base
    const int f   = row >> 12;                        // / NN
    const unsigned int k = (unsigned int)(keys[row] & 0xFFFFFFFFu);

    const float* __restrict__ q16 = wt + ((size_t)f * NK + k) * ND + c;
    const float* __restrict__ x16 = x_in + (size_t)row * ND + c;
    float* __restrict__ o16       = out + (size_t)row * ND + c;

    float lsum = 0.0f;
#pragma unroll
    for (int j = 0; j < 4; ++j) {
        float4 q  = *(const float4*)(q16 + 4 * j);
        float4 xv = *(const float4*)(x16 + 4 * j);
        const float dx0 = q.x - xv.x;
        const float dx1 = q.y - xv.y;
        const float dx2 = q.z - xv.z;
        const float dx3 = q.w - xv.w;
        lsum = fmaf(dx0, dx0, lsum);
        lsum = fmaf(dx1, dx1, lsum);
        lsum = fmaf(dx2, dx2, lsum);
        lsum = fmaf(dx3, dx3, lsum);
        *(float4*)(o16 + 4 * j) = q;
    }

#pragma unroll
    for (int off = 32; off > 0; off >>= 1) {
        lsum += __shfl_down(lsum, off, 64);
    }
    if ((threadIdx.x & 63) == 0) {
        atomicAdd(out + (size_t)NF * NN * ND, lsum * LOSS_SCALE);
    }
}

extern "C" void kernel_launch(void* const* d_in, const int* in_sizes, int n_in,
                              void* d_out, int out_size, void* d_ws, size_t ws_size,
                              hipStream_t stream) {
    const float* x_in = (const float*)d_in[0];  // [F, N, D] fp32
    const float* w    = (const float*)d_in[1];  // [F, D, K] fp32
    float* out        = (float*)d_out;          // [F*N*D] output then [1] loss

    float* wt  = (float*)d_ws;                               // [F,K,D] 4 MB
    float* w2h = wt + (size_t)NF * NK * ND;                  // [F,K]   64 KB
    unsigned long long* keys =
        (unsigned long long*)(w2h + (size_t)NF * NK);        // [F,N]   1 MB

    vq_prep1<<<NF * NK * 16 / 256, 256, 0, stream>>>(
        w, wt, keys, out + (size_t)NF * NN * ND);
    vq_prep2<<<NF * NK / 256, 256, 0, stream>>>(wt, w2h);

    dim3 grid(NN / 256, NF, KSPLIT);
    vq_argmin<<<grid, 256, 0, stream>>>(x_in, wt, w2h, keys);

    vq_gather<<<NF * NN * 4 / 256, 256, 0, stream>>>(x_in, wt, keys, out);
}

// Round 5
// 336.006 us; speedup vs baseline: 1.0842x; 1.0842x over previous
//
#include <hip/hip_runtime.h>
#include <math.h>

#define NF 32
#define NN 4096
#define ND 64
#define NK 512

// loss = q_latent + 0.25 * e_latent = 1.25 * mean((q - x)^2)
#define LOSS_SCALE (1.25f / (float)(NF * NN * ND))
// rescue margin: rows with approx top-2 gap < TAU get exact fp32 re-argmin.
// split-bf16 score error <= ~2^-16*||x||*||w||*3 ~ 6e-4 worst case; 2e-3 covers 2x.
#define TAU 2e-3f

typedef short bf16x8 __attribute__((ext_vector_type(8)));
typedef float f32x4 __attribute__((ext_vector_type(4)));

static __device__ __forceinline__ unsigned short f2bf_rne(float f) {
    unsigned int u = __float_as_uint(f);
    u += 0x7FFFu + ((u >> 16) & 1u);
    return (unsigned short)(u >> 16);
}
static __device__ __forceinline__ float bf2f(unsigned short h) {
    return __uint_as_float(((unsigned int)h) << 16);
}

// ---------------------------------------------------------------------------
// prep_w: wt[f][k][d] = w[f][d][k] (fp32, for rescue+gather);
//         wh/wl bf16 split of wt rows. thread per (f,k,d8): 512 blocks.
// ---------------------------------------------------------------------------
__global__ __launch_bounds__(256)
void vq_prep_w(const float* __restrict__ w, float* __restrict__ wt,
               unsigned short* __restrict__ wh, unsigned short* __restrict__ wl) {
    const int gid = blockIdx.x * 256 + threadIdx.x;   // [0, NF*NK*8)
    const int k  = gid & (NK - 1);
    const int dc = (gid >> 9) & 7;
    const int f  = gid >> 12;
    const float* __restrict__ wf = w + (size_t)f * ND * NK;
    const size_t rowo = ((size_t)f * NK + k) * ND + dc * 8;

    float v[8];
    unsigned short hh[8], ll[8];
#pragma unroll
    for (int j = 0; j < 8; ++j) {
        v[j] = wf[(dc * 8 + j) * NK + k];    // coalesced over k across lanes
        hh[j] = f2bf_rne(v[j]);
        ll[j] = f2bf_rne(v[j] - bf2f(hh[j]));
    }
    *(float4*)(wt + rowo)     = make_float4(v[0], v[1], v[2], v[3]);
    *(float4*)(wt + rowo + 4) = make_float4(v[4], v[5], v[6], v[7]);
    *(ushort4*)(wh + rowo)     = make_ushort4(hh[0], hh[1], hh[2], hh[3]);
    *(ushort4*)(wh + rowo + 4) = make_ushort4(hh[4], hh[5], hh[6], hh[7]);
    *(ushort4*)(wl + rowo)     = make_ushort4(ll[0], ll[1], ll[2], ll[3]);
    *(ushort4*)(wl + rowo + 4) = make_ushort4(ll[4], ll[5], ll[6], ll[7]);
}

// ---------------------------------------------------------------------------
// prep_w2: w2h[f][k] = 0.5*||w_k||^2 (fp32, exact, from wt rows);
//          zero loss slot + rescue count. thread per (f,k): 64 blocks.
// ---------------------------------------------------------------------------
__global__ __launch_bounds__(256)
void vq_prep_w2(const float* __restrict__ wt, float* __restrict__ w2h,
                float* __restrict__ loss_slot, unsigned int* __restrict__ rcount) {
    const int gid = blockIdx.x * 256 + threadIdx.x;   // [0, NF*NK)
    if (gid == 0) { *loss_slot = 0.0f; *rcount = 0u; }
    const float* __restrict__ r = wt + (size_t)gid * ND;
    float s = 0.0f;
#pragma unroll
    for (int d4 = 0; d4 < ND / 4; ++d4) {
        float4 v = *(const float4*)(r + 4 * d4);
        s = fmaf(v.x, v.x, s);
        s = fmaf(v.y, v.y, s);
        s = fmaf(v.z, v.z, s);
        s = fmaf(v.w, v.w, s);
    }
    w2h[gid] = 0.5f * s;
}

// ---------------------------------------------------------------------------
// argmin: block = 4 waves x 32 rows = 128 rows, all K=512 cols.
// score_k = 0.5||w_k||^2 - x.w_k via 6 MFMAs per 16-col tile per 16-row mtile
// (3 split terms x 2 ksteps), fp32 acc. Per-lane top-2 + idx tracking; final
// 16-lane merge. Rows with gap < TAU appended to rescue list.
// grid: (NN/128=32, NF=32) = 1024 blocks.
// ---------------------------------------------------------------------------
__global__ __launch_bounds__(256, 4)
void vq_argmin(const float* __restrict__ x_in,
               const unsigned short* __restrict__ wh,
               const unsigned short* __restrict__ wl,
               const float* __restrict__ w2h,
               unsigned int* __restrict__ keys,
               unsigned int* __restrict__ rlist,
               unsigned int* __restrict__ rcount) {
    const int f    = blockIdx.y;
    const int tid  = threadIdx.x;
    const int wave = tid >> 6;
    const int lane = tid & 63;
    const int lc   = lane & 15;
    const int q    = lane >> 4;
    const int n0   = blockIdx.x * 128 + wave * 32;

    __shared__ float w2s[NK];                 // 2 KB
    __shared__ unsigned short bstage[16384];  // 32 KB: 128 cols x 64 d x {h,l}

    for (int t = tid; t < NK; t += 256) w2s[t] = w2h[f * NK + t];

    // ---- A-frags: 32 rows' x, loaded once, split to bf16 hi/lo in-register
    // A[m = lane&15][k = q*8 + j] per kstep; mt selects rows n0+mt*16+lc.
    bf16x8 ah[2][2], al[2][2];
    const float* __restrict__ xbase = x_in + ((size_t)f * NN + n0 + lc) * ND;
#pragma unroll
    for (int mt = 0; mt < 2; ++mt) {
#pragma unroll
        for (int s = 0; s < 2; ++s) {
            const float* p = xbase + mt * 16 * ND + s * 32 + q * 8;
            float4 u0 = *(const float4*)(p);
            float4 u1 = *(const float4*)(p + 4);
            float xv[8] = {u0.x, u0.y, u0.z, u0.w, u1.x, u1.y, u1.z, u1.w};
            bf16x8 h, l;
#pragma unroll
            for (int j = 0; j < 8; ++j) {
                unsigned short hb = f2bf_rne(xv[j]);
                unsigned short lb = f2bf_rne(xv[j] - bf2f(hb));
                h[j] = (short)hb;
                l[j] = (short)lb;
            }
            ah[mt][s] = h;
            al[mt][s] = l;
        }
    }

    float m1[8], m2[8];
    int idx[8];
#pragma unroll
    for (int ri = 0; ri < 8; ++ri) { m1[ri] = INFINITY; m2[ri] = INFINITY; idx[ri] = 0; }

    for (int st = 0; st < 4; ++st) {          // supertiles of 128 cols
        __syncthreads();
        // stage wh/wl for cols [st*128, st*128+128) in frag-major order:
        // chunk ((tl*2+s)*2+a) holds 64 lanes x 8 bf16, lane-linear.
#pragma unroll
        for (int a = 0; a < 2; ++a) {
            const unsigned short* __restrict__ src =
                (a ? wl : wh) + ((size_t)f * NK + st * 128) * ND;
#pragma unroll
            for (int rep = 0; rep < 4; ++rep) {
                const int g   = tid + rep * 256;       // [0,1024) 16B chunks
                const int tl  = g >> 7;
                const int lcg = (g >> 3) & 15;
                const int sg  = (g >> 2) & 1;
                const int qg  = g & 3;
                const uint4 val =
                    *(const uint4*)(src + (size_t)(g >> 3) * ND + qg * 8 + sg * 32);
                *(uint4*)(bstage + ((tl * 2 + sg) * 2 + a) * 512 +
                          (qg * 16 + lcg) * 8) = val;
            }
        }
        __syncthreads();

#pragma unroll
        for (int tl = 0; tl < 8; ++tl) {
            const int colbase = st * 128 + tl * 16;
            const int col = colbase + lc;
            bf16x8 bh0 = *(const bf16x8*)(bstage + ((tl * 2 + 0) * 2 + 0) * 512 + lane * 8);
            bf16x8 bh1 = *(const bf16x8*)(bstage + ((tl * 2 + 1) * 2 + 0) * 512 + lane * 8);
            bf16x8 bl0 = *(const bf16x8*)(bstage + ((tl * 2 + 0) * 2 + 1) * 512 + lane * 8);
            bf16x8 bl1 = *(const bf16x8*)(bstage + ((tl * 2 + 1) * 2 + 1) * 512 + lane * 8);
            const float w2c = w2s[col];
#pragma unroll
            for (int mt = 0; mt < 2; ++mt) {
                f32x4 c = {0.f, 0.f, 0.f, 0.f};
                c = __builtin_amdgcn_mfma_f32_16x16x32_bf16(ah[mt][0], bh0, c, 0, 0, 0);
                c = __builtin_amdgcn_mfma_f32_16x16x32_bf16(ah[mt][1], bh1, c, 0, 0, 0);
                c = __builtin_amdgcn_mfma_f32_16x16x32_bf16(ah[mt][0], bl0, c, 0, 0, 0);
                c = __builtin_amdgcn_mfma_f32_16x16x32_bf16(ah[mt][1], bl1, c, 0, 0, 0);
                c = __builtin_amdgcn_mfma_f32_16x16x32_bf16(al[mt][0], bh0, c, 0, 0, 0);
                c = __builtin_amdgcn_mfma_f32_16x16x32_bf16(al[mt][1], bh1, c, 0, 0, 0);
#pragma unroll
                for (int r = 0; r < 4; ++r) {
                    const int ri = mt * 4 + r;
                    const float sc = w2c - c[r];
                    const float old1 = m1[ri];
                    const bool lt = sc < old1;             // strict: first idx wins
                    m1[ri]  = lt ? sc : old1;
                    m2[ri]  = fminf(m2[ri], fmaxf(sc, old1));
                    idx[ri] = lt ? col : idx[ri];
                }
            }
        }
    }

    // ---- merge top-2 across the 16 lanes holding each row ----
#pragma unroll
    for (int ri = 0; ri < 8; ++ri) {
        float a1 = m1[ri], a2 = m2[ri];
        int ai = idx[ri];
#pragma unroll
        for (int off = 1; off < 16; off <<= 1) {
            const float b1 = __shfl_xor(a1, off, 64);
            const float b2 = __shfl_xor(a2, off, 64);
            const int   bi = __shfl_xor(ai, off, 64);
            const float hi = fmaxf(a1, b1);
            const bool take = (b1 < a1) || (b1 == a1 && bi < ai);
            a1 = take ? b1 : a1;
            ai = take ? bi : ai;
            a2 = fminf(fminf(a2, b2), hi);
        }
        m1[ri] = a1; m2[ri] = a2; idx[ri] = ai;
    }

    if (lc == 0) {
#pragma unroll
        for (int ri = 0; ri < 8; ++ri) {
            const int mt = ri >> 2, r = ri & 3;
            const int g = f * NN + n0 + mt * 16 + q * 4 + r;
            keys[g] = (unsigned int)idx[ri];
            if (m2[ri] - m1[ri] < TAU) {
                const unsigned int pos = atomicAdd(rcount, 1u);
                rlist[pos] = (unsigned int)g;
            }
        }
    }
}

// ---------------------------------------------------------------------------
// rescue: exact fp32 full-K argmin for ambiguous rows. One wave per row,
// grid-stride over the compacted list. 256 blocks (1024 waves) fixed.
// ---------------------------------------------------------------------------
__global__ __launch_bounds__(256)
void vq_rescue(const float* __restrict__ x_in, const float* __restrict__ wt,
               const float* __restrict__ w2h,
               const unsigned int* __restrict__ rlist,
               const unsigned int* __restrict__ rcount,
               unsigned int* __restrict__ keys) {
    const int lane = threadIdx.x & 63;
    const unsigned int wid = (blockIdx.x * 256 + threadIdx.x) >> 6;
    const unsigned int nw  = (gridDim.x * 256) >> 6;
    const unsigned int cnt = *rcount;
    for (unsigned int i = wid; i < cnt; i += nw) {
        const unsigned int g = rlist[i];
        const int f = g >> 12;
        const float* __restrict__ xr  = x_in + (size_t)g * ND;
        const float* __restrict__ wtf = wt + (size_t)f * NK * ND;
        unsigned long long best = 0xFFFFFFFFFFFFFFFFULL;
#pragma unroll 1
        for (int j = 0; j < 8; ++j) {
            const int col = j * 64 + lane;
            const float* __restrict__ wr = wtf + (size_t)col * ND;
            float t = w2h[f * NK + col];
#pragma unroll
            for (int d = 0; d < ND; d += 4) {
                float4 xv = *(const float4*)(xr + d);   // broadcast across lanes
                float4 wv = *(const float4*)(wr + d);
                t = fmaf(-xv.x, wv.x, t);
                t = fmaf(-xv.y, wv.y, t);
                t = fmaf(-xv.z, wv.z, t);
                t = fmaf(-xv.w, wv.w, t);
            }
            unsigned int u = __float_as_uint(t);
            u ^= (unsigned int)((int)u >> 31) | 0x80000000u;
            const unsigned long long key =
                ((unsigned long long)u << 32) | (unsigned int)col;
            best = key < best ? key : best;
        }
#pragma unroll
        for (int off = 32; off > 0; off >>= 1) {
            const unsigned long long o = __shfl_xor(best, off, 64);
            best = o < best ? o : best;
        }
        if (lane == 0) keys[g] = (unsigned int)(best & 0xFFFFFFFFULL);
    }
}

// ---------------------------------------------------------------------------
// gather: 4 threads per row; straight-through output + loss. 2048 blocks.
// ---------------------------------------------------------------------------
__global__ __launch_bounds__(256)
void vq_gather(const float* __restrict__ x_in, const float* __restrict__ wt,
               const unsigned int* __restrict__ keys, float* __restrict__ out) {
    const int gid = blockIdx.x * 256 + threadIdx.x;   // [0, NF*NN*4)
    const int row = gid >> 2;
    const int c   = (gid & 3) * 16;
    const int f   = row >> 12;
    const unsigned int k = keys[row];

    const float* __restrict__ q16 = wt + ((size_t)f * NK + k) * ND + c;
    const float* __restrict__ x16 = x_in + (size_t)row * ND + c;
    float* __restrict__ o16       = out + (size_t)row * ND + c;

    float lsum = 0.0f;
#pragma unroll
    for (int j = 0; j < 4; ++j) {
        float4 qv = *(const float4*)(q16 + 4 * j);
        float4 xv = *(const float4*)(x16 + 4 * j);
        const float dx0 = qv.x - xv.x;
        const float dx1 = qv.y - xv.y;
        const float dx2 = qv.z - xv.z;
        const float dx3 = qv.w - xv.w;
        lsum = fmaf(dx0, dx0, lsum);
        lsum = fmaf(dx1, dx1, lsum);
        lsum = fmaf(dx2, dx2, lsum);
        lsum = fmaf(dx3, dx3, lsum);
        *(float4*)(o16 + 4 * j) = qv;
    }

#pragma unroll
    for (int off = 32; off > 0; off >>= 1) {
        lsum += __shfl_down(lsum, off, 64);
    }
    if ((threadIdx.x & 63) == 0) {
        atomicAdd(out + (size_t)NF * NN * ND, lsum * LOSS_SCALE);
    }
}

extern "C" void kernel_launch(void* const* d_in, const int* in_sizes, int n_in,
                              void* d_out, int out_size, void* d_ws, size_t ws_size,
                              hipStream_t stream) {
    const float* x_in = (const float*)d_in[0];  // [F, N, D] fp32
    const float* w    = (const float*)d_in[1];  // [F, D, K] fp32
    float* out        = (float*)d_out;          // [F*N*D] output then [1] loss

    float* wt  = (float*)d_ws;                                   // 4 MB
    float* w2h = wt + (size_t)NF * NK * ND;                      // 64 KB
    unsigned short* wh = (unsigned short*)(w2h + NF * NK);       // 2 MB
    unsigned short* wl = wh + (size_t)NF * NK * ND;              // 2 MB
    unsigned int* keys = (unsigned int*)(wl + (size_t)NF * NK * ND); // 512 KB
    unsigned int* rlist = keys + (size_t)NF * NN;                // 512 KB
    unsigned int* rcount = rlist + (size_t)NF * NN;

    float* loss_slot = out + (size_t)NF * NN * ND;

    vq_prep_w<<<NF * NK * 8 / 256, 256, 0, stream>>>(w, wt, wh, wl);
    vq_prep_w2<<<NF * NK / 256, 256, 0, stream>>>(wt, w2h, loss_slot, rcount);

    dim3 agrid(NN / 128, NF);
    vq_argmin<<<agrid, 256, 0, stream>>>(x_in, wh, wl, w2h, keys, rlist, rcount);

    vq_rescue<<<256, 256, 0, stream>>>(x_in, wt, w2h, rlist, rcount, keys);

    vq_gather<<<NF * NN * 4 / 256, 256, 0, stream>>>(x_in, wt, keys, out);
}

// Round 6
// 231.493 us; speedup vs baseline: 1.5737x; 1.4515x over previous
//
#include <hip/hip_runtime.h>
#include <math.h>

#define NF 32
#define NN 4096
#define ND 64
#define NK 512

// loss = q_latent + 0.25 * e_latent = 1.25 * mean((q - x)^2)
#define LOSS_SCALE (1.25f / (float)(NF * NN * ND))
// rescue margin: rows with approx top-2 gap < TAU get exact fp32 re-argmin.
// score-difference error bound ~1.2e-4 (split-bf16, missing xl*wl + fp32 acc
// rounding); 6e-4 gives 5x margin.
#define TAU 6e-4f

#define NPARTIAL (NF * NN * 4 / 256)   // 2048 gather blocks

typedef short bf16x8 __attribute__((ext_vector_type(8)));
typedef float f32x4 __attribute__((ext_vector_type(4)));

static __device__ __forceinline__ unsigned short f2bf_rne(float f) {
    unsigned int u = __float_as_uint(f);
    u += 0x7FFFu + ((u >> 16) & 1u);
    return (unsigned short)(u >> 16);
}
static __device__ __forceinline__ float bf2f(unsigned short h) {
    return __uint_as_float(((unsigned int)h) << 16);
}

// ---------------------------------------------------------------------------
// prep_w: wt[f][k][d] = w[f][d][k] (fp32, for rescue+gather);
//         wh/wl bf16 split of wt rows. thread per (f,k,d8): 512 blocks.
// ---------------------------------------------------------------------------
__global__ __launch_bounds__(256)
void vq_prep_w(const float* __restrict__ w, float* __restrict__ wt,
               unsigned short* __restrict__ wh, unsigned short* __restrict__ wl) {
    const int gid = blockIdx.x * 256 + threadIdx.x;   // [0, NF*NK*8)
    const int k  = gid & (NK - 1);
    const int dc = (gid >> 9) & 7;
    const int f  = gid >> 12;
    const float* __restrict__ wf = w + (size_t)f * ND * NK;
    const size_t rowo = ((size_t)f * NK + k) * ND + dc * 8;

    float v[8];
    unsigned short hh[8], ll[8];
#pragma unroll
    for (int j = 0; j < 8; ++j) {
        v[j] = wf[(dc * 8 + j) * NK + k];    // coalesced over k across lanes
        hh[j] = f2bf_rne(v[j]);
        ll[j] = f2bf_rne(v[j] - bf2f(hh[j]));
    }
    *(float4*)(wt + rowo)     = make_float4(v[0], v[1], v[2], v[3]);
    *(float4*)(wt + rowo + 4) = make_float4(v[4], v[5], v[6], v[7]);
    *(ushort4*)(wh + rowo)     = make_ushort4(hh[0], hh[1], hh[2], hh[3]);
    *(ushort4*)(wh + rowo + 4) = make_ushort4(hh[4], hh[5], hh[6], hh[7]);
    *(ushort4*)(wl + rowo)     = make_ushort4(ll[0], ll[1], ll[2], ll[3]);
    *(ushort4*)(wl + rowo + 4) = make_ushort4(ll[4], ll[5], ll[6], ll[7]);
}

// ---------------------------------------------------------------------------
// prep_w2: w2h[f][k] = 0.5*||w_k||^2 (fp32, exact). thread per (f,k).
// ---------------------------------------------------------------------------
__global__ __launch_bounds__(256)
void vq_prep_w2(const float* __restrict__ wt, float* __restrict__ w2h) {
    const int gid = blockIdx.x * 256 + threadIdx.x;   // [0, NF*NK)
    const float* __restrict__ r = wt + (size_t)gid * ND;
    float s = 0.0f;
#pragma unroll
    for (int d4 = 0; d4 < ND / 4; ++d4) {
        float4 v = *(const float4*)(r + 4 * d4);
        s = fmaf(v.x, v.x, s);
        s = fmaf(v.y, v.y, s);
        s = fmaf(v.z, v.z, s);
        s = fmaf(v.w, v.w, s);
    }
    w2h[gid] = 0.5f * s;
}

// ---------------------------------------------------------------------------
// argmin: block = 4 waves x 32 rows = 128 rows, all K=512 cols.
// score_k = 0.5||w_k||^2 - x.w_k via 6 MFMAs (3 split terms x 2 ksteps) per
// 16x16 tile, fp32 acc. Per-lane top-2+idx; 16-lane merge. Rows with
// gap < TAU get flags[g]=1 (no atomics). grid: (NN/128=32, NF=32).
// LDS B staging: chunk c = tl*4 + sg*2 + a holds 64 lanes x 16B, lane-linear
// (conflict-free writes AND reads).
// ---------------------------------------------------------------------------
__global__ __launch_bounds__(256, 4)
void vq_argmin(const float* __restrict__ x_in,
               const unsigned short* __restrict__ wh,
               const unsigned short* __restrict__ wl,
               const float* __restrict__ w2h,
               unsigned int* __restrict__ keys,
               unsigned char* __restrict__ flags) {
    const int f    = blockIdx.y;
    const int tid  = threadIdx.x;
    const int wave = tid >> 6;
    const int lane = tid & 63;
    const int lc   = lane & 15;
    const int q    = lane >> 4;
    const int n0   = blockIdx.x * 128 + wave * 32;

    __shared__ float w2s[NK];                 // 2 KB
    __shared__ unsigned short bstage[16384];  // 32 KB: 32 chunks x 512 shorts

    for (int t = tid; t < NK; t += 256) w2s[t] = w2h[f * NK + t];

    // ---- A-frags: 32 rows' x, loaded once, split to bf16 hi/lo in-register.
    // A[m = lane&15][k = q*8 + j] per kstep; mt selects rows n0+mt*16+lc.
    bf16x8 ah[2][2], al[2][2];
    const float* __restrict__ xbase = x_in + ((size_t)f * NN + n0 + lc) * ND;
#pragma unroll
    for (int mt = 0; mt < 2; ++mt) {
#pragma unroll
        for (int s = 0; s < 2; ++s) {
            const float* p = xbase + mt * 16 * ND + s * 32 + q * 8;
            float4 u0 = *(const float4*)(p);
            float4 u1 = *(const float4*)(p + 4);
            float xv[8] = {u0.x, u0.y, u0.z, u0.w, u1.x, u1.y, u1.z, u1.w};
            bf16x8 h, l;
#pragma unroll
            for (int j = 0; j < 8; ++j) {
                unsigned short hb = f2bf_rne(xv[j]);
                unsigned short lb = f2bf_rne(xv[j] - bf2f(hb));
                h[j] = (short)hb;
                l[j] = (short)lb;
            }
            ah[mt][s] = h;
            al[mt][s] = l;
        }
    }

    float m1[8], m2[8];
    int idx[8];
#pragma unroll
    for (int ri = 0; ri < 8; ++ri) { m1[ri] = INFINITY; m2[ri] = INFINITY; idx[ri] = 0; }

    for (int st = 0; st < 4; ++st) {          // supertiles of 128 cols
        __syncthreads();
        // stage: each wave writes 8 full 1KB chunks, lane-linear.
        // chunk c = tl*4 + sg*2 + a; lane (q,lc) supplies col tl*16+lc,
        // d-offsets q*8 + sg*32 .. +7.
#pragma unroll
        for (int rep = 0; rep < 8; ++rep) {
            const int c  = wave * 8 + rep;
            const int tl = c >> 2;
            const int sg = (c >> 1) & 1;
            const unsigned short* __restrict__ src =
                ((c & 1) ? wl : wh) + ((size_t)f * NK + st * 128) * ND;
            const uint4 val = *(const uint4*)(src +
                (size_t)(tl * 16 + lc) * ND + q * 8 + sg * 32);
            *(uint4*)(bstage + (size_t)c * 512 + lane * 8) = val;
        }
        __syncthreads();

#pragma unroll
        for (int tl = 0; tl < 8; ++tl) {
            const int col = st * 128 + tl * 16 + lc;
            bf16x8 bh0 = *(const bf16x8*)(bstage + (size_t)(tl * 4 + 0) * 512 + lane * 8);
            bf16x8 bl0 = *(const bf16x8*)(bstage + (size_t)(tl * 4 + 1) * 512 + lane * 8);
            bf16x8 bh1 = *(const bf16x8*)(bstage + (size_t)(tl * 4 + 2) * 512 + lane * 8);
            bf16x8 bl1 = *(const bf16x8*)(bstage + (size_t)(tl * 4 + 3) * 512 + lane * 8);
            const float w2c = w2s[col];
#pragma unroll
            for (int mt = 0; mt < 2; ++mt) {
                f32x4 c = {0.f, 0.f, 0.f, 0.f};
                c = __builtin_amdgcn_mfma_f32_16x16x32_bf16(ah[mt][0], bh0, c, 0, 0, 0);
                c = __builtin_amdgcn_mfma_f32_16x16x32_bf16(ah[mt][1], bh1, c, 0, 0, 0);
                c = __builtin_amdgcn_mfma_f32_16x16x32_bf16(ah[mt][0], bl0, c, 0, 0, 0);
                c = __builtin_amdgcn_mfma_f32_16x16x32_bf16(ah[mt][1], bl1, c, 0, 0, 0);
                c = __builtin_amdgcn_mfma_f32_16x16x32_bf16(al[mt][0], bh0, c, 0, 0, 0);
                c = __builtin_amdgcn_mfma_f32_16x16x32_bf16(al[mt][1], bh1, c, 0, 0, 0);
#pragma unroll
                for (int r = 0; r < 4; ++r) {
                    const int ri = mt * 4 + r;
                    const float sc = w2c - c[r];
                    const float old1 = m1[ri];
                    const bool lt = sc < old1;             // strict: first idx wins
                    m1[ri]  = lt ? sc : old1;
                    m2[ri]  = fminf(m2[ri], fmaxf(sc, old1));
                    idx[ri] = lt ? col : idx[ri];
                }
            }
        }
    }

    // ---- merge top-2 across the 16 lanes holding each row ----
#pragma unroll
    for (int ri = 0; ri < 8; ++ri) {
        float a1 = m1[ri], a2 = m2[ri];
        int ai = idx[ri];
#pragma unroll
        for (int off = 1; off < 16; off <<= 1) {
            const float b1 = __shfl_xor(a1, off, 64);
            const float b2 = __shfl_xor(a2, off, 64);
            const int   bi = __shfl_xor(ai, off, 64);
            const float hi = fmaxf(a1, b1);
            const bool take = (b1 < a1) || (b1 == a1 && bi < ai);
            a1 = take ? b1 : a1;
            ai = take ? bi : ai;
            a2 = fminf(fminf(a2, b2), hi);
        }
        m1[ri] = a1; m2[ri] = a2; idx[ri] = ai;
    }

    if (lc == 0) {
#pragma unroll
        for (int mt = 0; mt < 2; ++mt) {
            const int g = f * NN + n0 + mt * 16 + q * 4;   // 4 consecutive rows
            uint4 kv;
            kv.x = (unsigned int)idx[mt * 4 + 0];
            kv.y = (unsigned int)idx[mt * 4 + 1];
            kv.z = (unsigned int)idx[mt * 4 + 2];
            kv.w = (unsigned int)idx[mt * 4 + 3];
            *(uint4*)(keys + g) = kv;
            uchar4 fl;
            fl.x = (m2[mt * 4 + 0] - m1[mt * 4 + 0] < TAU) ? 1 : 0;
            fl.y = (m2[mt * 4 + 1] - m1[mt * 4 + 1] < TAU) ? 1 : 0;
            fl.z = (m2[mt * 4 + 2] - m1[mt * 4 + 2] < TAU) ? 1 : 0;
            fl.w = (m2[mt * 4 + 3] - m1[mt * 4 + 3] < TAU) ? 1 : 0;
            *(uchar4*)(flags + g) = fl;
        }
    }
}

// ---------------------------------------------------------------------------
// rescue: exact fp32 full-K argmin for flagged rows. One wave per 64-row
// group: ballot the flags, full-wave rescan per set row. No atomics.
// grid: 512 blocks = 2048 waves = NF*NN/64 groups.
// ---------------------------------------------------------------------------
__global__ __launch_bounds__(256)
void vq_rescue(const float* __restrict__ x_in, const float* __restrict__ wt,
               const float* __restrict__ w2h,
               const unsigned char* __restrict__ flags,
               unsigned int* __restrict__ keys) {
    const int lane = threadIdx.x & 63;
    const int wid  = (blockIdx.x * 256 + threadIdx.x) >> 6;  // [0, 2048)
    const int base = wid * 64;

    unsigned long long m = __ballot(flags[base + lane] != 0);
    while (m) {
        const int r = __ffsll(m) - 1;
        m &= m - 1;
        const int g = base + r;
        const int f = g >> 12;                               // / NN
        const float* __restrict__ xr  = x_in + (size_t)g * ND;
        const float* __restrict__ wtf = wt + (size_t)f * NK * ND;
        unsigned long long best = 0xFFFFFFFFFFFFFFFFULL;
#pragma unroll 1
        for (int j = 0; j < 8; ++j) {
            const int col = j * 64 + lane;
            const float* __restrict__ wr = wtf + (size_t)col * ND;
            float t = w2h[f * NK + col];
#pragma unroll
            for (int d = 0; d < ND; d += 4) {
                float4 xv = *(const float4*)(xr + d);   // broadcast
                float4 wv = *(const float4*)(wr + d);
                t = fmaf(-xv.x, wv.x, t);
                t = fmaf(-xv.y, wv.y, t);
                t = fmaf(-xv.z, wv.z, t);
                t = fmaf(-xv.w, wv.w, t);
            }
            unsigned int u = __float_as_uint(t);
            u ^= (unsigned int)((int)u >> 31) | 0x80000000u;
            const unsigned long long key =
                ((unsigned long long)u << 32) | (unsigned int)col;
            best = key < best ? key : best;
        }
#pragma unroll
        for (int off = 32; off > 0; off >>= 1) {
            const unsigned long long o = __shfl_xor(best, off, 64);
            best = o < best ? o : best;
        }
        if (lane == 0) keys[g] = (unsigned int)(best & 0xFFFFFFFFULL);
    }
}

// ---------------------------------------------------------------------------
// gather: 4 threads per row; straight-through output. Per-block loss partial
// (plain store, no atomics). 2048 blocks.
// ---------------------------------------------------------------------------
__global__ __launch_bounds__(256)
void vq_gather(const float* __restrict__ x_in, const float* __restrict__ wt,
               const unsigned int* __restrict__ keys, float* __restrict__ out,
               float* __restrict__ partial) {
    const int gid = blockIdx.x * 256 + threadIdx.x;   // [0, NF*NN*4)
    const int row = gid >> 2;
    const int c   = (gid & 3) * 16;
    const int f   = row >> 12;
    const unsigned int k = keys[row];

    const float* __restrict__ q16 = wt + ((size_t)f * NK + k) * ND + c;
    const float* __restrict__ x16 = x_in + (size_t)row * ND + c;
    float* __restrict__ o16       = out + (size_t)row * ND + c;

    float lsum = 0.0f;
#pragma unroll
    for (int j = 0; j < 4; ++j) {
        float4 qv = *(const float4*)(q16 + 4 * j);
        float4 xv = *(const float4*)(x16 + 4 * j);
        const float dx0 = qv.x - xv.x;
        const float dx1 = qv.y - xv.y;
        const float dx2 = qv.z - xv.z;
        const float dx3 = qv.w - xv.w;
        lsum = fmaf(dx0, dx0, lsum);
        lsum = fmaf(dx1, dx1, lsum);
        lsum = fmaf(dx2, dx2, lsum);
        lsum = fmaf(dx3, dx3, lsum);
        *(float4*)(o16 + 4 * j) = qv;
    }

#pragma unroll
    for (int off = 32; off > 0; off >>= 1) {
        lsum += __shfl_down(lsum, off, 64);
    }
    __shared__ float wsum[4];
    if ((threadIdx.x & 63) == 0) wsum[threadIdx.x >> 6] = lsum;
    __syncthreads();
    if (threadIdx.x == 0) {
        partial[blockIdx.x] = wsum[0] + wsum[1] + wsum[2] + wsum[3];
    }
}

// ---------------------------------------------------------------------------
// loss_final: sum 2048 partials -> loss scalar. 1 block.
// ---------------------------------------------------------------------------
__global__ __launch_bounds__(256)
void vq_loss_final(const float* __restrict__ partial, float* __restrict__ loss) {
    float s = 0.0f;
    for (int i = threadIdx.x; i < NPARTIAL; i += 256) s += partial[i];
#pragma unroll
    for (int off = 32; off > 0; off >>= 1) s += __shfl_down(s, off, 64);
    __shared__ float wsum[4];
    if ((threadIdx.x & 63) == 0) wsum[threadIdx.x >> 6] = s;
    __syncthreads();
    if (threadIdx.x == 0) {
        *loss = (wsum[0] + wsum[1] + wsum[2] + wsum[3]) * LOSS_SCALE;
    }
}

extern "C" void kernel_launch(void* const* d_in, const int* in_sizes, int n_in,
                              void* d_out, int out_size, void* d_ws, size_t ws_size,
                              hipStream_t stream) {
    const float* x_in = (const float*)d_in[0];  // [F, N, D] fp32
    const float* w    = (const float*)d_in[1];  // [F, D, K] fp32
    float* out        = (float*)d_out;          // [F*N*D] output then [1] loss

    float* wt  = (float*)d_ws;                                   // 4 MB
    float* w2h = wt + (size_t)NF * NK * ND;                      // 64 KB
    unsigned short* wh = (unsigned short*)(w2h + NF * NK);       // 2 MB
    unsigned short* wl = wh + (size_t)NF * NK * ND;              // 2 MB
    unsigned int* keys = (unsigned int*)(wl + (size_t)NF * NK * ND); // 512 KB
    unsigned char* flags = (unsigned char*)(keys + (size_t)NF * NN); // 128 KB
    float* partial = (float*)(flags + (size_t)NF * NN);          // 8 KB

    float* loss_slot = out + (size_t)NF * NN * ND;

    vq_prep_w<<<NF * NK * 8 / 256, 256, 0, stream>>>(w, wt, wh, wl);
    vq_prep_w2<<<NF * NK / 256, 256, 0, stream>>>(wt, w2h);

    dim3 agrid(NN / 128, NF);
    vq_argmin<<<agrid, 256, 0, stream>>>(x_in, wh, wl, w2h, keys, flags);

    vq_rescue<<<NF * NN / 64 / 4, 256, 0, stream>>>(x_in, wt, w2h, flags, keys);

    vq_gather<<<NF * NN * 4 / 256, 256, 0, stream>>>(x_in, wt, keys, out, partial);

    vq_loss_final<<<1, 256, 0, stream>>>(partial, loss_slot);
}

// Round 7
// 183.787 us; speedup vs baseline: 1.9822x; 1.2596x over previous
//
#include <hip/hip_runtime.h>
#include <math.h>

#define NF 32
#define NN 4096
#define ND 64
#define NK 512

// loss = q_latent + 0.25 * e_latent = 1.25 * mean((q - x)^2)
#define LOSS_SCALE (1.25f / (float)(NF * NN * ND))
// rescue margin: rows with approx top-2 gap < TAU get exact fp32 re-argmin.
#define TAU 6e-4f

#define NPARTIAL (NF * NN * 4 / 256)   // 2048 gather blocks

typedef short bf16x8 __attribute__((ext_vector_type(8)));
typedef float f32x4 __attribute__((ext_vector_type(4)));

static __device__ __forceinline__ unsigned short f2bf_rne(float f) {
    unsigned int u = __float_as_uint(f);
    u += 0x7FFFu + ((u >> 16) & 1u);
    return (unsigned short)(u >> 16);
}
static __device__ __forceinline__ float bf2f(unsigned short h) {
    return __uint_as_float(((unsigned int)h) << 16);
}

// ---------------------------------------------------------------------------
// prep_w: wt[f][k][d] = w[f][d][k] (fp32, for rescue+gather);
//         wh/wl bf16 split of wt rows. thread per (f,k,d8): 512 blocks.
// ---------------------------------------------------------------------------
__global__ __launch_bounds__(256)
void vq_prep_w(const float* __restrict__ w, float* __restrict__ wt,
               unsigned short* __restrict__ wh, unsigned short* __restrict__ wl) {
    const int gid = blockIdx.x * 256 + threadIdx.x;   // [0, NF*NK*8)
    const int k  = gid & (NK - 1);
    const int dc = (gid >> 9) & 7;
    const int f  = gid >> 12;
    const float* __restrict__ wf = w + (size_t)f * ND * NK;
    const size_t rowo = ((size_t)f * NK + k) * ND + dc * 8;

    float v[8];
    unsigned short hh[8], ll[8];
#pragma unroll
    for (int j = 0; j < 8; ++j) {
        v[j] = wf[(dc * 8 + j) * NK + k];    // coalesced over k across lanes
        hh[j] = f2bf_rne(v[j]);
        ll[j] = f2bf_rne(v[j] - bf2f(hh[j]));
    }
    *(float4*)(wt + rowo)     = make_float4(v[0], v[1], v[2], v[3]);
    *(float4*)(wt + rowo + 4) = make_float4(v[4], v[5], v[6], v[7]);
    *(ushort4*)(wh + rowo)     = make_ushort4(hh[0], hh[1], hh[2], hh[3]);
    *(ushort4*)(wh + rowo + 4) = make_ushort4(hh[4], hh[5], hh[6], hh[7]);
    *(ushort4*)(wl + rowo)     = make_ushort4(ll[0], ll[1], ll[2], ll[3]);
    *(ushort4*)(wl + rowo + 4) = make_ushort4(ll[4], ll[5], ll[6], ll[7]);
}

// ---------------------------------------------------------------------------
// prep_w2: w2h[f][k] = 0.5*||w_k||^2 (fp32, exact). thread per (f,k).
// ---------------------------------------------------------------------------
__global__ __launch_bounds__(256)
void vq_prep_w2(const float* __restrict__ wt, float* __restrict__ w2h) {
    const int gid = blockIdx.x * 256 + threadIdx.x;   // [0, NF*NK)
    const float* __restrict__ r = wt + (size_t)gid * ND;
    float s = 0.0f;
#pragma unroll
    for (int d4 = 0; d4 < ND / 4; ++d4) {
        float4 v = *(const float4*)(r + 4 * d4);
        s = fmaf(v.x, v.x, s);
        s = fmaf(v.y, v.y, s);
        s = fmaf(v.z, v.z, s);
        s = fmaf(v.w, v.w, s);
    }
    w2h[gid] = 0.5f * s;
}

// ---------------------------------------------------------------------------
// argmin: block = 4 waves x 32 rows = 128 rows, all K=512 cols.
// score_k = 0.5||w_k||^2 - x.w_k via 6 MFMAs (3 split terms x 2 ksteps) per
// 16x16 tile, fp32 acc. Per-lane top-2+idx; 16-lane merge. Rows with
// gap < TAU get flags[g]=1. 1-D grid of 1024 blocks, XCD-swizzled so all 32
// row-blocks of one f land on one XCD (B data stays hot in its 4MB L2).
// __launch_bounds__(256,2): 256-VGPR budget -> NO scratch spill (R6: the
// (256,4) hint made the allocator target 8 waves/EU=64 VGPR and spill 184MB
// to HBM; LDS caps us at 4 waves/SIMD regardless).
// ---------------------------------------------------------------------------
__global__ __launch_bounds__(256, 2)
void vq_argmin(const float* __restrict__ x_in,
               const unsigned short* __restrict__ wh,
               const unsigned short* __restrict__ wl,
               const float* __restrict__ w2h,
               unsigned int* __restrict__ keys,
               unsigned char* __restrict__ flags) {
    // XCD swizzle: xcd = b&7 (round-robin dispatch), 4 f's per XCD.
    const int b    = blockIdx.x;
    const int g8   = b >> 3;
    const int f    = (b & 7) * 4 + (g8 >> 5);
    const int xt   = g8 & 31;
    const int tid  = threadIdx.x;
    const int wave = tid >> 6;
    const int lane = tid & 63;
    const int lc   = lane & 15;
    const int q    = lane >> 4;
    const int n0   = xt * 128 + wave * 32;

    __shared__ float w2s[NK];                 // 2 KB
    __shared__ unsigned short bstage[16384];  // 32 KB: 32 chunks x 512 shorts

    for (int t = tid; t < NK; t += 256) w2s[t] = w2h[f * NK + t];

    // ---- A-frags: 32 rows' x, loaded once, split to bf16 hi/lo in-register.
    // A[m = lane&15][k = q*8 + j] per kstep; mt selects rows n0+mt*16+lc.
    bf16x8 ah[2][2], al[2][2];
    const float* __restrict__ xbase = x_in + ((size_t)f * NN + n0 + lc) * ND;
#pragma unroll
    for (int mt = 0; mt < 2; ++mt) {
#pragma unroll
        for (int s = 0; s < 2; ++s) {
            const float* p = xbase + mt * 16 * ND + s * 32 + q * 8;
            float4 u0 = *(const float4*)(p);
            float4 u1 = *(const float4*)(p + 4);
            float xv[8] = {u0.x, u0.y, u0.z, u0.w, u1.x, u1.y, u1.z, u1.w};
            bf16x8 h, l;
#pragma unroll
            for (int j = 0; j < 8; ++j) {
                unsigned short hb = f2bf_rne(xv[j]);
                unsigned short lb = f2bf_rne(xv[j] - bf2f(hb));
                h[j] = (short)hb;
                l[j] = (short)lb;
            }
            ah[mt][s] = h;
            al[mt][s] = l;
        }
    }

    float m1[8], m2[8];
    int idx[8];
#pragma unroll
    for (int ri = 0; ri < 8; ++ri) { m1[ri] = INFINITY; m2[ri] = INFINITY; idx[ri] = 0; }

    for (int st = 0; st < 4; ++st) {          // supertiles of 128 cols
        __syncthreads();
        // stage: each wave writes 8 full 1KB chunks, lane-linear
        // (conflict-free). chunk c = tl*4 + sg*2 + a.
#pragma unroll
        for (int rep = 0; rep < 8; ++rep) {
            const int c  = wave * 8 + rep;
            const int tl = c >> 2;
            const int sg = (c >> 1) & 1;
            const unsigned short* __restrict__ src =
                ((c & 1) ? wl : wh) + ((size_t)f * NK + st * 128) * ND;
            const uint4 val = *(const uint4*)(src +
                (size_t)(tl * 16 + lc) * ND + q * 8 + sg * 32);
            *(uint4*)(bstage + (size_t)c * 512 + lane * 8) = val;
        }
        __syncthreads();

#pragma unroll
        for (int tl = 0; tl < 8; ++tl) {
            const int col = st * 128 + tl * 16 + lc;
            bf16x8 bh0 = *(const bf16x8*)(bstage + (size_t)(tl * 4 + 0) * 512 + lane * 8);
            bf16x8 bl0 = *(const bf16x8*)(bstage + (size_t)(tl * 4 + 1) * 512 + lane * 8);
            bf16x8 bh1 = *(const bf16x8*)(bstage + (size_t)(tl * 4 + 2) * 512 + lane * 8);
            bf16x8 bl1 = *(const bf16x8*)(bstage + (size_t)(tl * 4 + 3) * 512 + lane * 8);
            const float w2c = w2s[col];
#pragma unroll
            for (int mt = 0; mt < 2; ++mt) {
                f32x4 c = {0.f, 0.f, 0.f, 0.f};
                c = __builtin_amdgcn_mfma_f32_16x16x32_bf16(ah[mt][0], bh0, c, 0, 0, 0);
                c = __builtin_amdgcn_mfma_f32_16x16x32_bf16(ah[mt][1], bh1, c, 0, 0, 0);
                c = __builtin_amdgcn_mfma_f32_16x16x32_bf16(ah[mt][0], bl0, c, 0, 0, 0);
                c = __builtin_amdgcn_mfma_f32_16x16x32_bf16(ah[mt][1], bl1, c, 0, 0, 0);
                c = __builtin_amdgcn_mfma_f32_16x16x32_bf16(al[mt][0], bh0, c, 0, 0, 0);
                c = __builtin_amdgcn_mfma_f32_16x16x32_bf16(al[mt][1], bh1, c, 0, 0, 0);
#pragma unroll
                for (int r = 0; r < 4; ++r) {
                    const int ri = mt * 4 + r;
                    const float sc = w2c - c[r];
                    const float old1 = m1[ri];
                    const bool lt = sc < old1;             // strict: first idx wins
                    m1[ri]  = lt ? sc : old1;
                    m2[ri]  = fminf(m2[ri], fmaxf(sc, old1));
                    idx[ri] = lt ? col : idx[ri];
                }
            }
        }
    }

    // ---- merge top-2 across the 16 lanes holding each row ----
#pragma unroll
    for (int ri = 0; ri < 8; ++ri) {
        float a1 = m1[ri], a2 = m2[ri];
        int ai = idx[ri];
#pragma unroll
        for (int off = 1; off < 16; off <<= 1) {
            const float b1 = __shfl_xor(a1, off, 64);
            const float b2 = __shfl_xor(a2, off, 64);
            const int   bi = __shfl_xor(ai, off, 64);
            const float hi = fmaxf(a1, b1);
            const bool take = (b1 < a1) || (b1 == a1 && bi < ai);
            a1 = take ? b1 : a1;
            ai = take ? bi : ai;
            a2 = fminf(fminf(a2, b2), hi);
        }
        m1[ri] = a1; m2[ri] = a2; idx[ri] = ai;
    }

    if (lc == 0) {
#pragma unroll
        for (int mt = 0; mt < 2; ++mt) {
            const int g = f * NN + n0 + mt * 16 + q * 4;   // 4 consecutive rows
            uint4 kv;
            kv.x = (unsigned int)idx[mt * 4 + 0];
            kv.y = (unsigned int)idx[mt * 4 + 1];
            kv.z = (unsigned int)idx[mt * 4 + 2];
            kv.w = (unsigned int)idx[mt * 4 + 3];
            *(uint4*)(keys + g) = kv;
            uchar4 fl;
            fl.x = (m2[mt * 4 + 0] - m1[mt * 4 + 0] < TAU) ? 1 : 0;
            fl.y = (m2[mt * 4 + 1] - m1[mt * 4 + 1] < TAU) ? 1 : 0;
            fl.z = (m2[mt * 4 + 2] - m1[mt * 4 + 2] < TAU) ? 1 : 0;
            fl.w = (m2[mt * 4 + 3] - m1[mt * 4 + 3] < TAU) ? 1 : 0;
            *(uchar4*)(flags + g) = fl;
        }
    }
}

// ---------------------------------------------------------------------------
// rescue: exact fp32 full-K argmin for flagged rows. One wave per 64-row
// group: ballot the flags, full-wave rescan per set row. No atomics.
// ---------------------------------------------------------------------------
__global__ __launch_bounds__(256)
void vq_rescue(const float* __restrict__ x_in, const float* __restrict__ wt,
               const float* __restrict__ w2h,
               const unsigned char* __restrict__ flags,
               unsigned int* __restrict__ keys) {
    const int lane = threadIdx.x & 63;
    const int wid  = (blockIdx.x * 256 + threadIdx.x) >> 6;  // [0, 2048)
    const int base = wid * 64;

    unsigned long long m = __ballot(flags[base + lane] != 0);
    while (m) {
        const int r = __ffsll(m) - 1;
        m &= m - 1;
        const int g = base + r;
        const int f = g >> 12;                               // / NN
        const float* __restrict__ xr  = x_in + (size_t)g * ND;
        const float* __restrict__ wtf = wt + (size_t)f * NK * ND;
        unsigned long long best = 0xFFFFFFFFFFFFFFFFULL;
#pragma unroll 1
        for (int j = 0; j < 8; ++j) {
            const int col = j * 64 + lane;
            const float* __restrict__ wr = wtf + (size_t)col * ND;
            float t = w2h[f * NK + col];
#pragma unroll
            for (int d = 0; d < ND; d += 4) {
                float4 xv = *(const float4*)(xr + d);   // broadcast
                float4 wv = *(const float4*)(wr + d);
                t = fmaf(-xv.x, wv.x, t);
                t = fmaf(-xv.y, wv.y, t);
                t = fmaf(-xv.z, wv.z, t);
                t = fmaf(-xv.w, wv.w, t);
            }
            unsigned int u = __float_as_uint(t);
            u ^= (unsigned int)((int)u >> 31) | 0x80000000u;
            const unsigned long long key =
                ((unsigned long long)u << 32) | (unsigned int)col;
            best = key < best ? key : best;
        }
#pragma unroll
        for (int off = 32; off > 0; off >>= 1) {
            const unsigned long long o = __shfl_xor(best, off, 64);
            best = o < best ? o : best;
        }
        if (lane == 0) keys[g] = (unsigned int)(best & 0xFFFFFFFFULL);
    }
}

// ---------------------------------------------------------------------------
// gather: 4 threads per row; straight-through output. Per-block loss partial
// (plain store, no atomics). 2048 blocks.
// ---------------------------------------------------------------------------
__global__ __launch_bounds__(256)
void vq_gather(const float* __restrict__ x_in, const float* __restrict__ wt,
               const unsigned int* __restrict__ keys, float* __restrict__ out,
               float* __restrict__ partial) {
    const int gid = blockIdx.x * 256 + threadIdx.x;   // [0, NF*NN*4)
    const int row = gid >> 2;
    const int c   = (gid & 3) * 16;
    const int f   = row >> 12;
    const unsigned int k = keys[row];

    const float* __restrict__ q16 = wt + ((size_t)f * NK + k) * ND + c;
    const float* __restrict__ x16 = x_in + (size_t)row * ND + c;
    float* __restrict__ o16       = out + (size_t)row * ND + c;

    float lsum = 0.0f;
#pragma unroll
    for (int j = 0; j < 4; ++j) {
        float4 qv = *(const float4*)(q16 + 4 * j);
        float4 xv = *(const float4*)(x16 + 4 * j);
        const float dx0 = qv.x - xv.x;
        const float dx1 = qv.y - xv.y;
        const float dx2 = qv.z - xv.z;
        const float dx3 = qv.w - xv.w;
        lsum = fmaf(dx0, dx0, lsum);
        lsum = fmaf(dx1, dx1, lsum);
        lsum = fmaf(dx2, dx2, lsum);
        lsum = fmaf(dx3, dx3, lsum);
        *(float4*)(o16 + 4 * j) = qv;
    }

#pragma unroll
    for (int off = 32; off > 0; off >>= 1) {
        lsum += __shfl_down(lsum, off, 64);
    }
    __shared__ float wsum[4];
    if ((threadIdx.x & 63) == 0) wsum[threadIdx.x >> 6] = lsum;
    __syncthreads();
    if (threadIdx.x == 0) {
        partial[blockIdx.x] = wsum[0] + wsum[1] + wsum[2] + wsum[3];
    }
}

// ---------------------------------------------------------------------------
// loss_final: sum 2048 partials -> loss scalar. 1 block.
// ---------------------------------------------------------------------------
__global__ __launch_bounds__(256)
void vq_loss_final(const float* __restrict__ partial, float* __restrict__ loss) {
    float s = 0.0f;
    for (int i = threadIdx.x; i < NPARTIAL; i += 256) s += partial[i];
#pragma unroll
    for (int off = 32; off > 0; off >>= 1) s += __shfl_down(s, off, 64);
    __shared__ float wsum[4];
    if ((threadIdx.x & 63) == 0) wsum[threadIdx.x >> 6] = s;
    __syncthreads();
    if (threadIdx.x == 0) {
        *loss = (wsum[0] + wsum[1] + wsum[2] + wsum[3]) * LOSS_SCALE;
    }
}

extern "C" void kernel_launch(void* const* d_in, const int* in_sizes, int n_in,
                              void* d_out, int out_size, void* d_ws, size_t ws_size,
                              hipStream_t stream) {
    const float* x_in = (const float*)d_in[0];  // [F, N, D] fp32
    const float* w    = (const float*)d_in[1];  // [F, D, K] fp32
    float* out        = (float*)d_out;          // [F*N*D] output then [1] loss

    float* wt  = (float*)d_ws;                                   // 4 MB
    float* w2h = wt + (size_t)NF * NK * ND;                      // 64 KB
    unsigned short* wh = (unsigned short*)(w2h + NF * NK);       // 2 MB
    unsigned short* wl = wh + (size_t)NF * NK * ND;              // 2 MB
    unsigned int* keys = (unsigned int*)(wl + (size_t)NF * NK * ND); // 512 KB
    unsigned char* flags = (unsigned char*)(keys + (size_t)NF * NN); // 128 KB
    float* partial = (float*)(flags + (size_t)NF * NN);          // 8 KB

    float* loss_slot = out + (size_t)NF * NN * ND;

    vq_prep_w<<<NF * NK * 8 / 256, 256, 0, stream>>>(w, wt, wh, wl);
    vq_prep_w2<<<NF * NK / 256, 256, 0, stream>>>(wt, w2h);

    vq_argmin<<<NF * NN / 128, 256, 0, stream>>>(x_in, wh, wl, w2h, keys, flags);

    vq_rescue<<<NF * NN / 64 / 4, 256, 0, stream>>>(x_in, wt, w2h, flags, keys);

    vq_gather<<<NF * NN * 4 / 256, 256, 0, stream>>>(x_in, wt, keys, out, partial);

    vq_loss_final<<<1, 256, 0, stream>>>(partial, loss_slot);
}

// Round 8
// 174.822 us; speedup vs baseline: 2.0838x; 1.0513x over previous
//
#include <hip/hip_runtime.h>
#include <math.h>

#define NF 32
#define NN 4096
#define ND 64
#define NK 512

// loss = q_latent + 0.25 * e_latent = 1.25 * mean((q - x)^2)
#define LOSS_SCALE (1.25f / (float)(NF * NN * ND))
// rescue margin: rows with approx top-2 gap < TAU get exact fp32 re-argmin.
#define TAU 6e-4f

#define NPARTIAL (NF * NN * 4 / 256)   // 2048 gather blocks

typedef short bf16x8 __attribute__((ext_vector_type(8)));
typedef float f32x4 __attribute__((ext_vector_type(4)));

static __device__ __forceinline__ unsigned short f2bf_rne(float f) {
    unsigned int u = __float_as_uint(f);
    u += 0x7FFFu + ((u >> 16) & 1u);
    return (unsigned short)(u >> 16);
}
static __device__ __forceinline__ float bf2f(unsigned short h) {
    return __uint_as_float(((unsigned int)h) << 16);
}

// async global->LDS: 16B per lane, dest = wave-uniform base + lane*16
static __device__ __forceinline__ void gload_lds16(const void* g, void* l) {
    __builtin_amdgcn_global_load_lds(
        (const __attribute__((address_space(1))) unsigned int*)g,
        (__attribute__((address_space(3))) unsigned int*)l, 16, 0, 0);
}

// ---------------------------------------------------------------------------
// prep_w: wt[f][k][d] = w[f][d][k] (fp32, for rescue+gather);
//         wh/wl bf16 split of wt rows. thread per (f,k,d8): 512 blocks.
// ---------------------------------------------------------------------------
__global__ __launch_bounds__(256)
void vq_prep_w(const float* __restrict__ w, float* __restrict__ wt,
               unsigned short* __restrict__ wh, unsigned short* __restrict__ wl) {
    const int gid = blockIdx.x * 256 + threadIdx.x;   // [0, NF*NK*8)
    const int k  = gid & (NK - 1);
    const int dc = (gid >> 9) & 7;
    const int f  = gid >> 12;
    const float* __restrict__ wf = w + (size_t)f * ND * NK;
    const size_t rowo = ((size_t)f * NK + k) * ND + dc * 8;

    float v[8];
    unsigned short hh[8], ll[8];
#pragma unroll
    for (int j = 0; j < 8; ++j) {
        v[j] = wf[(dc * 8 + j) * NK + k];    // coalesced over k across lanes
        hh[j] = f2bf_rne(v[j]);
        ll[j] = f2bf_rne(v[j] - bf2f(hh[j]));
    }
    *(float4*)(wt + rowo)     = make_float4(v[0], v[1], v[2], v[3]);
    *(float4*)(wt + rowo + 4) = make_float4(v[4], v[5], v[6], v[7]);
    *(ushort4*)(wh + rowo)     = make_ushort4(hh[0], hh[1], hh[2], hh[3]);
    *(ushort4*)(wh + rowo + 4) = make_ushort4(hh[4], hh[5], hh[6], hh[7]);
    *(ushort4*)(wl + rowo)     = make_ushort4(ll[0], ll[1], ll[2], ll[3]);
    *(ushort4*)(wl + rowo + 4) = make_ushort4(ll[4], ll[5], ll[6], ll[7]);
}

// ---------------------------------------------------------------------------
// prep_w2: w2h[f][k] = 0.5*||w_k||^2 (fp32, exact). thread per (f,k).
// ---------------------------------------------------------------------------
__global__ __launch_bounds__(256)
void vq_prep_w2(const float* __restrict__ wt, float* __restrict__ w2h) {
    const int gid = blockIdx.x * 256 + threadIdx.x;   // [0, NF*NK)
    const float* __restrict__ r = wt + (size_t)gid * ND;
    float s = 0.0f;
#pragma unroll
    for (int d4 = 0; d4 < ND / 4; ++d4) {
        float4 v = *(const float4*)(r + 4 * d4);
        s = fmaf(v.x, v.x, s);
        s = fmaf(v.y, v.y, s);
        s = fmaf(v.z, v.z, s);
        s = fmaf(v.w, v.w, s);
    }
    w2h[gid] = 0.5f * s;
}

// ---------------------------------------------------------------------------
// argmin: block = 4 waves x 32 rows = 128 rows, all K=512 cols.
// acc init = -0.5||w_k||^2, MFMA accumulates +x.w (3 split terms x 2 ksteps)
// -> c = dot - w2c = -score; neg folds into cmp/med3 src modifiers (free).
// B staged in 64-col supertiles, DOUBLE-BUFFERED via async global_load_lds:
// loads for st+1 are in flight during compute of st, one barrier per st.
// LDS dest layout is lane-linear 16B chunks = exactly the global_load_lds
// wave-uniform-base + lane*16 constraint.
// XCD swizzle: all 32 row-blocks of one f on one XCD (B hot in 4MB L2).
// (256,2): 256-VGPR budget, no spill (R6 lesson).
// ---------------------------------------------------------------------------
__global__ __launch_bounds__(256, 2)
void vq_argmin(const float* __restrict__ x_in,
               const unsigned short* __restrict__ wh,
               const unsigned short* __restrict__ wl,
               const float* __restrict__ w2h,
               unsigned int* __restrict__ keys,
               unsigned char* __restrict__ flags) {
    const int b    = blockIdx.x;
    const int g8   = b >> 3;
    const int f    = (b & 7) * 4 + (g8 >> 5);
    const int xt   = g8 & 31;
    const int tid  = threadIdx.x;
    const int wave = tid >> 6;
    const int lane = tid & 63;
    const int lc   = lane & 15;
    const int q    = lane >> 4;
    const int n0   = xt * 128 + wave * 32;

    __shared__ float nw2s[NK];                            // 2 KB (negated)
    __shared__ __align__(16) unsigned short bstage[2][8192];  // 2 x 16 KB

    for (int t = tid; t < NK; t += 256) nw2s[t] = -w2h[f * NK + t];

    // ---- A-frags: 32 rows' x, loaded once, split to bf16 hi/lo in-register.
    bf16x8 ah[2][2], al[2][2];
    const float* __restrict__ xbase = x_in + ((size_t)f * NN + n0 + lc) * ND;
#pragma unroll
    for (int mt = 0; mt < 2; ++mt) {
#pragma unroll
        for (int s = 0; s < 2; ++s) {
            const float* p = xbase + mt * 16 * ND + s * 32 + q * 8;
            float4 u0 = *(const float4*)(p);
            float4 u1 = *(const float4*)(p + 4);
            float xv[8] = {u0.x, u0.y, u0.z, u0.w, u1.x, u1.y, u1.z, u1.w};
            bf16x8 h, l;
#pragma unroll
            for (int j = 0; j < 8; ++j) {
                unsigned short hb = f2bf_rne(xv[j]);
                unsigned short lb = f2bf_rne(xv[j] - bf2f(hb));
                h[j] = (short)hb;
                l[j] = (short)lb;
            }
            ah[mt][s] = h;
            al[mt][s] = l;
        }
    }

    const unsigned short* __restrict__ whf = wh + (size_t)f * NK * ND;
    const unsigned short* __restrict__ wlf = wl + (size_t)f * NK * ND;

    float m1[8], m2[8];
    int idx[8];
#pragma unroll
    for (int ri = 0; ri < 8; ++ri) { m1[ri] = INFINITY; m2[ri] = INFINITY; idx[ri] = 0; }

    // ---- stage supertile st (64 cols) into bstage[pb]: 16 chunks of 1KB,
    // 4 per wave. chunk c = tl*4 + sg*2 + a; slot i<-lane(q=i>>4,lc=i&15).
#define STAGE(st, pb) do {                                                  \
    _Pragma("unroll")                                                       \
    for (int rep = 0; rep < 4; ++rep) {                                     \
        const int c  = wave * 4 + rep;                                      \
        const int tl = c >> 2;                                              \
        const int sg = (c >> 1) & 1;                                        \
        const unsigned short* src = ((c & 1) ? wlf : whf) +                 \
            (size_t)((st) * 64 + tl * 16 + lc) * ND + q * 8 + sg * 32;      \
        gload_lds16(src, &bstage[pb][c * 512]);                             \
    }                                                                       \
} while (0)

    STAGE(0, 0);

    for (int st = 0; st < 8; ++st) {
        __syncthreads();                 // drains this st's loads (vmcnt)
        if (st < 7) STAGE(st + 1, (st + 1) & 1);
        const unsigned short* __restrict__ bb = &bstage[st & 1][0];

#pragma unroll
        for (int tl = 0; tl < 4; ++tl) {
            const int col = st * 64 + tl * 16 + lc;
            bf16x8 bh0 = *(const bf16x8*)(bb + (tl * 4 + 0) * 512 + lane * 8);
            bf16x8 bl0 = *(const bf16x8*)(bb + (tl * 4 + 1) * 512 + lane * 8);
            bf16x8 bh1 = *(const bf16x8*)(bb + (tl * 4 + 2) * 512 + lane * 8);
            bf16x8 bl1 = *(const bf16x8*)(bb + (tl * 4 + 3) * 512 + lane * 8);
            const float nw2 = nw2s[col];
#pragma unroll
            for (int mt = 0; mt < 2; ++mt) {
                f32x4 c = {nw2, nw2, nw2, nw2};
                c = __builtin_amdgcn_mfma_f32_16x16x32_bf16(ah[mt][0], bh0, c, 0, 0, 0);
                c = __builtin_amdgcn_mfma_f32_16x16x32_bf16(ah[mt][1], bh1, c, 0, 0, 0);
                c = __builtin_amdgcn_mfma_f32_16x16x32_bf16(ah[mt][0], bl0, c, 0, 0, 0);
                c = __builtin_amdgcn_mfma_f32_16x16x32_bf16(ah[mt][1], bl1, c, 0, 0, 0);
                c = __builtin_amdgcn_mfma_f32_16x16x32_bf16(al[mt][0], bh0, c, 0, 0, 0);
                c = __builtin_amdgcn_mfma_f32_16x16x32_bf16(al[mt][1], bh1, c, 0, 0, 0);
#pragma unroll
                for (int r = 0; r < 4; ++r) {
                    const int ri = mt * 4 + r;
                    const float sc = -c[r];                    // folds into mods
                    const bool lt = sc < m1[ri];               // strict: first idx
                    m2[ri]  = __builtin_amdgcn_fmed3f(sc, m1[ri], m2[ri]);
                    m1[ri]  = lt ? sc : m1[ri];
                    idx[ri] = lt ? col : idx[ri];
                }
            }
        }
    }

    // ---- merge top-2 across the 16 lanes holding each row ----
#pragma unroll
    for (int ri = 0; ri < 8; ++ri) {
        float a1 = m1[ri], a2 = m2[ri];
        int ai = idx[ri];
#pragma unroll
        for (int off = 1; off < 16; off <<= 1) {
            const float b1 = __shfl_xor(a1, off, 64);
            const float b2 = __shfl_xor(a2, off, 64);
            const int   bi = __shfl_xor(ai, off, 64);
            const float hi = fmaxf(a1, b1);
            const bool take = (b1 < a1) || (b1 == a1 && bi < ai);
            a1 = take ? b1 : a1;
            ai = take ? bi : ai;
            a2 = fminf(fminf(a2, b2), hi);
        }
        m1[ri] = a1; m2[ri] = a2; idx[ri] = ai;
    }

    if (lc == 0) {
#pragma unroll
        for (int mt = 0; mt < 2; ++mt) {
            const int g = f * NN + n0 + mt * 16 + q * 4;   // 4 consecutive rows
            uint4 kv;
            kv.x = (unsigned int)idx[mt * 4 + 0];
            kv.y = (unsigned int)idx[mt * 4 + 1];
            kv.z = (unsigned int)idx[mt * 4 + 2];
            kv.w = (unsigned int)idx[mt * 4 + 3];
            *(uint4*)(keys + g) = kv;
            uchar4 fl;
            fl.x = (m2[mt * 4 + 0] - m1[mt * 4 + 0] < TAU) ? 1 : 0;
            fl.y = (m2[mt * 4 + 1] - m1[mt * 4 + 1] < TAU) ? 1 : 0;
            fl.z = (m2[mt * 4 + 2] - m1[mt * 4 + 2] < TAU) ? 1 : 0;
            fl.w = (m2[mt * 4 + 3] - m1[mt * 4 + 3] < TAU) ? 1 : 0;
            *(uchar4*)(flags + g) = fl;
        }
    }
}

// ---------------------------------------------------------------------------
// rescue: exact fp32 full-K argmin for flagged rows. One wave per 64-row
// group: ballot the flags, full-wave rescan per set row. No atomics.
// ---------------------------------------------------------------------------
__global__ __launch_bounds__(256)
void vq_rescue(const float* __restrict__ x_in, const float* __restrict__ wt,
               const float* __restrict__ w2h,
               const unsigned char* __restrict__ flags,
               unsigned int* __restrict__ keys) {
    const int lane = threadIdx.x & 63;
    const int wid  = (blockIdx.x * 256 + threadIdx.x) >> 6;  // [0, 2048)
    const int base = wid * 64;

    unsigned long long m = __ballot(flags[base + lane] != 0);
    while (m) {
        const int r = __ffsll(m) - 1;
        m &= m - 1;
        const int g = base + r;
        const int f = g >> 12;                               // / NN
        const float* __restrict__ xr  = x_in + (size_t)g * ND;
        const float* __restrict__ wtf = wt + (size_t)f * NK * ND;
        unsigned long long best = 0xFFFFFFFFFFFFFFFFULL;
#pragma unroll 1
        for (int j = 0; j < 8; ++j) {
            const int col = j * 64 + lane;
            const float* __restrict__ wr = wtf + (size_t)col * ND;
            float t = w2h[f * NK + col];
#pragma unroll
            for (int d = 0; d < ND; d += 4) {
                float4 xv = *(const float4*)(xr + d);   // broadcast
                float4 wv = *(const float4*)(wr + d);
                t = fmaf(-xv.x, wv.x, t);
                t = fmaf(-xv.y, wv.y, t);
                t = fmaf(-xv.z, wv.z, t);
                t = fmaf(-xv.w, wv.w, t);
            }
            unsigned int u = __float_as_uint(t);
            u ^= (unsigned int)((int)u >> 31) | 0x80000000u;
            const unsigned long long key =
                ((unsigned long long)u << 32) | (unsigned int)col;
            best = key < best ? key : best;
        }
#pragma unroll
        for (int off = 32; off > 0; off >>= 1) {
            const unsigned long long o = __shfl_xor(best, off, 64);
            best = o < best ? o : best;
        }
        if (lane == 0) keys[g] = (unsigned int)(best & 0xFFFFFFFFULL);
    }
}

// ---------------------------------------------------------------------------
// gather: 4 threads per row; straight-through output. Per-block loss partial
// (plain store, no atomics). 2048 blocks.
// ---------------------------------------------------------------------------
__global__ __launch_bounds__(256)
void vq_gather(const float* __restrict__ x_in, const float* __restrict__ wt,
               const unsigned int* __restrict__ keys, float* __restrict__ out,
               float* __restrict__ partial) {
    const int gid = blockIdx.x * 256 + threadIdx.x;   // [0, NF*NN*4)
    const int row = gid >> 2;
    const int c   = (gid & 3) * 16;
    const int f   = row >> 12;
    const unsigned int k = keys[row];

    const float* __restrict__ q16 = wt + ((size_t)f * NK + k) * ND + c;
    const float* __restrict__ x16 = x_in + (size_t)row * ND + c;
    float* __restrict__ o16       = out + (size_t)row * ND + c;

    float lsum = 0.0f;
#pragma unroll
    for (int j = 0; j < 4; ++j) {
        float4 qv = *(const float4*)(q16 + 4 * j);
        float4 xv = *(const float4*)(x16 + 4 * j);
        const float dx0 = qv.x - xv.x;
        const float dx1 = qv.y - xv.y;
        const float dx2 = qv.z - xv.z;
        const float dx3 = qv.w - xv.w;
        lsum = fmaf(dx0, dx0, lsum);
        lsum = fmaf(dx1, dx1, lsum);
        lsum = fmaf(dx2, dx2, lsum);
        lsum = fmaf(dx3, dx3, lsum);
        *(float4*)(o16 + 4 * j) = qv;
    }

#pragma unroll
    for (int off = 32; off > 0; off >>= 1) {
        lsum += __shfl_down(lsum, off, 64);
    }
    __shared__ float wsum[4];
    if ((threadIdx.x & 63) == 0) wsum[threadIdx.x >> 6] = lsum;
    __syncthreads();
    if (threadIdx.x == 0) {
        partial[blockIdx.x] = wsum[0] + wsum[1] + wsum[2] + wsum[3];
    }
}

// ---------------------------------------------------------------------------
// loss_final: sum 2048 partials -> loss scalar. 1 block.
// ---------------------------------------------------------------------------
__global__ __launch_bounds__(256)
void vq_loss_final(const float* __restrict__ partial, float* __restrict__ loss) {
    float s = 0.0f;
    for (int i = threadIdx.x; i < NPARTIAL; i += 256) s += partial[i];
#pragma unroll
    for (int off = 32; off > 0; off >>= 1) s += __shfl_down(s, off, 64);
    __shared__ float wsum[4];
    if ((threadIdx.x & 63) == 0) wsum[threadIdx.x >> 6] = s;
    __syncthreads();
    if (threadIdx.x == 0) {
        *loss = (wsum[0] + wsum[1] + wsum[2] + wsum[3]) * LOSS_SCALE;
    }
}

extern "C" void kernel_launch(void* const* d_in, const int* in_sizes, int n_in,
                              void* d_out, int out_size, void* d_ws, size_t ws_size,
                              hipStream_t stream) {
    const float* x_in = (const float*)d_in[0];  // [F, N, D] fp32
    const float* w    = (const float*)d_in[1];  // [F, D, K] fp32
    float* out        = (float*)d_out;          // [F*N*D] output then [1] loss

    float* wt  = (float*)d_ws;                                   // 4 MB
    float* w2h = wt + (size_t)NF * NK * ND;                      // 64 KB
    unsigned short* wh = (unsigned short*)(w2h + NF * NK);       // 2 MB
    unsigned short* wl = wh + (size_t)NF * NK * ND;              // 2 MB
    unsigned int* keys = (unsigned int*)(wl + (size_t)NF * NK * ND); // 512 KB
    unsigned char* flags = (unsigned char*)(keys + (size_t)NF * NN); // 128 KB
    float* partial = (float*)(flags + (size_t)NF * NN);          // 8 KB

    float* loss_slot = out + (size_t)NF * NN * ND;

    vq_prep_w<<<NF * NK * 8 / 256, 256, 0, stream>>>(w, wt, wh, wl);
    vq_prep_w2<<<NF * NK / 256, 256, 0, stream>>>(wt, w2h);

    vq_argmin<<<NF * NN / 128, 256, 0, stream>>>(x_in, wh, wl, w2h, keys, flags);

    vq_rescue<<<NF * NN / 64 / 4, 256, 0, stream>>>(x_in, wt, w2h, flags, keys);

    vq_gather<<<NF * NN * 4 / 256, 256, 0, stream>>>(x_in, wt, keys, out, partial);

    vq_loss_final<<<1, 256, 0, stream>>>(partial, loss_slot);
}

// Round 9
// 170.559 us; speedup vs baseline: 2.1359x; 1.0250x over previous
//
#include <hip/hip_runtime.h>
#include <math.h>

#define NF 32
#define NN 4096
#define ND 64
#define NK 512

// loss = q_latent + 0.25 * e_latent = 1.25 * mean((q - x)^2)
#define LOSS_SCALE (1.25f / (float)(NF * NN * ND))
// rescue margin: rows with approx top-2 gap < TAU get exact fp32 re-argmin.
#define TAU 6e-4f

#define NPARTIAL (NF * NN * 4 / 256)   // 2048 gather blocks

typedef short bf16x8 __attribute__((ext_vector_type(8)));
typedef float f32x4 __attribute__((ext_vector_type(4)));

static __device__ __forceinline__ unsigned short f2bf_rne(float f) {
    unsigned int u = __float_as_uint(f);
    u += 0x7FFFu + ((u >> 16) & 1u);
    return (unsigned short)(u >> 16);
}
static __device__ __forceinline__ float bf2f(unsigned short h) {
    return __uint_as_float(((unsigned int)h) << 16);
}

// async global->LDS: 16B per lane, dest = wave-uniform base + lane*16
static __device__ __forceinline__ void gload_lds16(const void* g, void* l) {
    __builtin_amdgcn_global_load_lds(
        (const __attribute__((address_space(1))) unsigned int*)g,
        (__attribute__((address_space(3))) unsigned int*)l, 16, 0, 0);
}

// ---------------------------------------------------------------------------
// prep_w (fused): wt[f][k][d] = w[f][d][k]; wh/wl bf16 split; w2h = 0.5||w||^2
// via 8-lane shuffle reduce (dc lives in lane bits 0..2 -> contiguous wt/wh/wl
// writes, in-wave norm reduction). thread per (f,k,dc): 512 blocks.
// ---------------------------------------------------------------------------
__global__ __launch_bounds__(256)
void vq_prep_w(const float* __restrict__ w, float* __restrict__ wt,
               unsigned short* __restrict__ wh, unsigned short* __restrict__ wl,
               float* __restrict__ w2h) {
    const int gid = blockIdx.x * 256 + threadIdx.x;   // [0, NF*NK*8)
    const int dc = gid & 7;
    const int k  = (gid >> 3) & (NK - 1);
    const int f  = gid >> 12;
    const float* __restrict__ wf = w + (size_t)f * ND * NK;
    const size_t rowo = ((size_t)f * NK + k) * ND + dc * 8;

    float v[8];
    unsigned short hh[8], ll[8];
    float s = 0.0f;
#pragma unroll
    for (int j = 0; j < 8; ++j) {
        v[j] = wf[(dc * 8 + j) * NK + k];
        s = fmaf(v[j], v[j], s);
        hh[j] = f2bf_rne(v[j]);
        ll[j] = f2bf_rne(v[j] - bf2f(hh[j]));
    }
    *(float4*)(wt + rowo)     = make_float4(v[0], v[1], v[2], v[3]);
    *(float4*)(wt + rowo + 4) = make_float4(v[4], v[5], v[6], v[7]);
    *(ushort4*)(wh + rowo)     = make_ushort4(hh[0], hh[1], hh[2], hh[3]);
    *(ushort4*)(wh + rowo + 4) = make_ushort4(hh[4], hh[5], hh[6], hh[7]);
    *(ushort4*)(wl + rowo)     = make_ushort4(ll[0], ll[1], ll[2], ll[3]);
    *(ushort4*)(wl + rowo + 4) = make_ushort4(ll[4], ll[5], ll[6], ll[7]);

    // reduce ||w_k||^2 over the 8 dc-lanes (dc == lane & 7)
    s += __shfl_xor(s, 1, 64);
    s += __shfl_xor(s, 2, 64);
    s += __shfl_xor(s, 4, 64);
    if (dc == 0) w2h[f * NK + k] = 0.5f * s;
}

// ---------------------------------------------------------------------------
// argmin: block = 4 waves x 64 rows = 256 rows, all K=512 cols.
// mt=4 register tile: halves per-row LDS B-traffic vs mt=2 (R8's floor was
// the 4x-redundant ds_read stream, ~10us/CU). acc init = -0.5||w_k||^2, MFMA
// accumulates +x.w (3 split terms x 2 ksteps) -> sc = -c. B staged in 64-col
// supertiles, double-buffered via async global_load_lds (lane-linear dest).
// XCD swizzle: all 16 row-blocks of one f on one XCD. (256,2): no spill.
// grid: 512 blocks = 2 blocks/CU.
// ---------------------------------------------------------------------------
__global__ __launch_bounds__(256, 2)
void vq_argmin(const float* __restrict__ x_in,
               const unsigned short* __restrict__ wh,
               const unsigned short* __restrict__ wl,
               const float* __restrict__ w2h,
               unsigned int* __restrict__ keys,
               unsigned char* __restrict__ flags) {
    const int b    = blockIdx.x;          // [0, 512)
    const int g8   = b >> 3;              // [0, 64)
    const int f    = (b & 7) * 4 + (g8 >> 4);
    const int xt   = g8 & 15;
    const int tid  = threadIdx.x;
    const int wave = tid >> 6;
    const int lane = tid & 63;
    const int lc   = lane & 15;
    const int q    = lane >> 4;
    const int n0   = xt * 256 + wave * 64;   // wave owns rows n0..n0+63

    __shared__ float nw2s[NK];                            // 2 KB (negated)
    __shared__ __align__(16) unsigned short bstage[2][8192];  // 2 x 16 KB

    for (int t = tid; t < NK; t += 256) nw2s[t] = -w2h[f * NK + t];

    // ---- A-frags: 64 rows' x, loaded once, split to bf16 hi/lo in-register.
    // A[m = lane&15][k = q*8 + j] per kstep; mt selects rows n0+mt*16+lc.
    bf16x8 ah[4][2], al[4][2];
    const float* __restrict__ xbase = x_in + ((size_t)f * NN + n0 + lc) * ND;
#pragma unroll
    for (int mt = 0; mt < 4; ++mt) {
#pragma unroll
        for (int s = 0; s < 2; ++s) {
            const float* p = xbase + mt * 16 * ND + s * 32 + q * 8;
            float4 u0 = *(const float4*)(p);
            float4 u1 = *(const float4*)(p + 4);
            float xv[8] = {u0.x, u0.y, u0.z, u0.w, u1.x, u1.y, u1.z, u1.w};
            bf16x8 h, l;
#pragma unroll
            for (int j = 0; j < 8; ++j) {
                unsigned short hb = f2bf_rne(xv[j]);
                unsigned short lb = f2bf_rne(xv[j] - bf2f(hb));
                h[j] = (short)hb;
                l[j] = (short)lb;
            }
            ah[mt][s] = h;
            al[mt][s] = l;
        }
    }

    const unsigned short* __restrict__ whf = wh + (size_t)f * NK * ND;
    const unsigned short* __restrict__ wlf = wl + (size_t)f * NK * ND;

    float m1[16], m2[16];
    int idx[16];
#pragma unroll
    for (int ri = 0; ri < 16; ++ri) { m1[ri] = INFINITY; m2[ri] = INFINITY; idx[ri] = 0; }

    // ---- stage supertile st (64 cols) into bstage[pb]: 16 chunks of 1KB,
    // 4 per wave. chunk c = tl*4 + sg*2 + a.
#define STAGE(st, pb) do {                                                  \
    _Pragma("unroll")                                                       \
    for (int rep = 0; rep < 4; ++rep) {                                     \
        const int c  = wave * 4 + rep;                                      \
        const int tl = c >> 2;                                              \
        const int sg = (c >> 1) & 1;                                        \
        const unsigned short* src = ((c & 1) ? wlf : whf) +                 \
            (size_t)((st) * 64 + tl * 16 + lc) * ND + q * 8 + sg * 32;      \
        gload_lds16(src, &bstage[pb][c * 512]);                             \
    }                                                                       \
} while (0)

    STAGE(0, 0);

    for (int st = 0; st < 8; ++st) {
        __syncthreads();                 // drains this st's loads
        if (st < 7) STAGE(st + 1, (st + 1) & 1);
        const unsigned short* __restrict__ bb = &bstage[st & 1][0];

#pragma unroll
        for (int tl = 0; tl < 4; ++tl) {
            const int col = st * 64 + tl * 16 + lc;
            bf16x8 bh0 = *(const bf16x8*)(bb + (tl * 4 + 0) * 512 + lane * 8);
            bf16x8 bl0 = *(const bf16x8*)(bb + (tl * 4 + 1) * 512 + lane * 8);
            bf16x8 bh1 = *(const bf16x8*)(bb + (tl * 4 + 2) * 512 + lane * 8);
            bf16x8 bl1 = *(const bf16x8*)(bb + (tl * 4 + 3) * 512 + lane * 8);
            const float nw2 = nw2s[col];
#pragma unroll
            for (int mt = 0; mt < 4; ++mt) {
                f32x4 c = {nw2, nw2, nw2, nw2};
                c = __builtin_amdgcn_mfma_f32_16x16x32_bf16(ah[mt][0], bh0, c, 0, 0, 0);
                c = __builtin_amdgcn_mfma_f32_16x16x32_bf16(ah[mt][1], bh1, c, 0, 0, 0);
                c = __builtin_amdgcn_mfma_f32_16x16x32_bf16(ah[mt][0], bl0, c, 0, 0, 0);
                c = __builtin_amdgcn_mfma_f32_16x16x32_bf16(ah[mt][1], bl1, c, 0, 0, 0);
                c = __builtin_amdgcn_mfma_f32_16x16x32_bf16(al[mt][0], bh0, c, 0, 0, 0);
                c = __builtin_amdgcn_mfma_f32_16x16x32_bf16(al[mt][1], bh1, c, 0, 0, 0);
#pragma unroll
                for (int r = 0; r < 4; ++r) {
                    const int ri = mt * 4 + r;
                    const float sc = -c[r];                    // folds into mods
                    const bool lt = sc < m1[ri];               // strict: first idx
                    m2[ri]  = __builtin_amdgcn_fmed3f(sc, m1[ri], m2[ri]);
                    m1[ri]  = lt ? sc : m1[ri];
                    idx[ri] = lt ? col : idx[ri];
                }
            }
        }
    }

    // ---- merge top-2 across the 16 lanes holding each row ----
#pragma unroll
    for (int ri = 0; ri < 16; ++ri) {
        float a1 = m1[ri], a2 = m2[ri];
        int ai = idx[ri];
#pragma unroll
        for (int off = 1; off < 16; off <<= 1) {
            const float b1 = __shfl_xor(a1, off, 64);
            const float b2 = __shfl_xor(a2, off, 64);
            const int   bi = __shfl_xor(ai, off, 64);
            const float hi = fmaxf(a1, b1);
            const bool take = (b1 < a1) || (b1 == a1 && bi < ai);
            a1 = take ? b1 : a1;
            ai = take ? bi : ai;
            a2 = fminf(fminf(a2, b2), hi);
        }
        m1[ri] = a1; m2[ri] = a2; idx[ri] = ai;
    }

    if (lc == 0) {
#pragma unroll
        for (int mt = 0; mt < 4; ++mt) {
            const int g = f * NN + n0 + mt * 16 + q * 4;   // 4 consecutive rows
            uint4 kv;
            kv.x = (unsigned int)idx[mt * 4 + 0];
            kv.y = (unsigned int)idx[mt * 4 + 1];
            kv.z = (unsigned int)idx[mt * 4 + 2];
            kv.w = (unsigned int)idx[mt * 4 + 3];
            *(uint4*)(keys + g) = kv;
            uchar4 fl;
            fl.x = (m2[mt * 4 + 0] - m1[mt * 4 + 0] < TAU) ? 1 : 0;
            fl.y = (m2[mt * 4 + 1] - m1[mt * 4 + 1] < TAU) ? 1 : 0;
            fl.z = (m2[mt * 4 + 2] - m1[mt * 4 + 2] < TAU) ? 1 : 0;
            fl.w = (m2[mt * 4 + 3] - m1[mt * 4 + 3] < TAU) ? 1 : 0;
            *(uchar4*)(flags + g) = fl;
        }
    }
}

// ---------------------------------------------------------------------------
// rescue: exact fp32 full-K argmin for flagged rows. One wave per 64-row
// group: ballot the flags, full-wave rescan per set row. No atomics.
// ---------------------------------------------------------------------------
__global__ __launch_bounds__(256)
void vq_rescue(const float* __restrict__ x_in, const float* __restrict__ wt,
               const float* __restrict__ w2h,
               const unsigned char* __restrict__ flags,
               unsigned int* __restrict__ keys) {
    const int lane = threadIdx.x & 63;
    const int wid  = (blockIdx.x * 256 + threadIdx.x) >> 6;  // [0, 2048)
    const int base = wid * 64;

    unsigned long long m = __ballot(flags[base + lane] != 0);
    while (m) {
        const int r = __ffsll(m) - 1;
        m &= m - 1;
        const int g = base + r;
        const int f = g >> 12;                               // / NN
        const float* __restrict__ xr  = x_in + (size_t)g * ND;
        const float* __restrict__ wtf = wt + (size_t)f * NK * ND;
        unsigned long long best = 0xFFFFFFFFFFFFFFFFULL;
#pragma unroll 1
        for (int j = 0; j < 8; ++j) {
            const int col = j * 64 + lane;
            const float* __restrict__ wr = wtf + (size_t)col * ND;
            float t = w2h[f * NK + col];
#pragma unroll
            for (int d = 0; d < ND; d += 4) {
                float4 xv = *(const float4*)(xr + d);   // broadcast
                float4 wv = *(const float4*)(wr + d);
                t = fmaf(-xv.x, wv.x, t);
                t = fmaf(-xv.y, wv.y, t);
                t = fmaf(-xv.z, wv.z, t);
                t = fmaf(-xv.w, wv.w, t);
            }
            unsigned int u = __float_as_uint(t);
            u ^= (unsigned int)((int)u >> 31) | 0x80000000u;
            const unsigned long long key =
                ((unsigned long long)u << 32) | (unsigned int)col;
            best = key < best ? key : best;
        }
#pragma unroll
        for (int off = 32; off > 0; off >>= 1) {
            const unsigned long long o = __shfl_xor(best, off, 64);
            best = o < best ? o : best;
        }
        if (lane == 0) keys[g] = (unsigned int)(best & 0xFFFFFFFFULL);
    }
}

// ---------------------------------------------------------------------------
// gather: 4 threads per row; straight-through output. Per-block loss partial
// (plain store, no atomics). 2048 blocks.
// ---------------------------------------------------------------------------
__global__ __launch_bounds__(256)
void vq_gather(const float* __restrict__ x_in, const float* __restrict__ wt,
               const unsigned int* __restrict__ keys, float* __restrict__ out,
               float* __restrict__ partial) {
    const int gid = blockIdx.x * 256 + threadIdx.x;   // [0, NF*NN*4)
    const int row = gid >> 2;
    const int c   = (gid & 3) * 16;
    const int f   = row >> 12;
    const unsigned int k = keys[row];

    const float* __restrict__ q16 = wt + ((size_t)f * NK + k) * ND + c;
    const float* __restrict__ x16 = x_in + (size_t)row * ND + c;
    float* __restrict__ o16       = out + (size_t)row * ND + c;

    float lsum = 0.0f;
#pragma unroll
    for (int j = 0; j < 4; ++j) {
        float4 qv = *(const float4*)(q16 + 4 * j);
        float4 xv = *(const float4*)(x16 + 4 * j);
        const float dx0 = qv.x - xv.x;
        const float dx1 = qv.y - xv.y;
        const float dx2 = qv.z - xv.z;
        const float dx3 = qv.w - xv.w;
        lsum = fmaf(dx0, dx0, lsum);
        lsum = fmaf(dx1, dx1, lsum);
        lsum = fmaf(dx2, dx2, lsum);
        lsum = fmaf(dx3, dx3, lsum);
        *(float4*)(o16 + 4 * j) = qv;
    }

#pragma unroll
    for (int off = 32; off > 0; off >>= 1) {
        lsum += __shfl_down(lsum, off, 64);
    }
    __shared__ float wsum[4];
    if ((threadIdx.x & 63) == 0) wsum[threadIdx.x >> 6] = lsum;
    __syncthreads();
    if (threadIdx.x == 0) {
        partial[blockIdx.x] = wsum[0] + wsum[1] + wsum[2] + wsum[3];
    }
}

// ---------------------------------------------------------------------------
// loss_final: sum 2048 partials -> loss scalar. 1 block.
// ---------------------------------------------------------------------------
__global__ __launch_bounds__(256)
void vq_loss_final(const float* __restrict__ partial, float* __restrict__ loss) {
    float s = 0.0f;
    for (int i = threadIdx.x; i < NPARTIAL; i += 256) s += partial[i];
#pragma unroll
    for (int off = 32; off > 0; off >>= 1) s += __shfl_down(s, off, 64);
    __shared__ float wsum[4];
    if ((threadIdx.x & 63) == 0) wsum[threadIdx.x >> 6] = s;
    __syncthreads();
    if (threadIdx.x == 0) {
        *loss = (wsum[0] + wsum[1] + wsum[2] + wsum[3]) * LOSS_SCALE;
    }
}

extern "C" void kernel_launch(void* const* d_in, const int* in_sizes, int n_in,
                              void* d_out, int out_size, void* d_ws, size_t ws_size,
                              hipStream_t stream) {
    const float* x_in = (const float*)d_in[0];  // [F, N, D] fp32
    const float* w    = (const float*)d_in[1];  // [F, D, K] fp32
    float* out        = (float*)d_out;          // [F*N*D] output then [1] loss

    float* wt  = (float*)d_ws;                                   // 4 MB
    float* w2h = wt + (size_t)NF * NK * ND;                      // 64 KB
    unsigned short* wh = (unsigned short*)(w2h + NF * NK);       // 2 MB
    unsigned short* wl = wh + (size_t)NF * NK * ND;              // 2 MB
    unsigned int* keys = (unsigned int*)(wl + (size_t)NF * NK * ND); // 512 KB
    unsigned char* flags = (unsigned char*)(keys + (size_t)NF * NN); // 128 KB
    float* partial = (float*)(flags + (size_t)NF * NN);          // 8 KB

    float* loss_slot = out + (size_t)NF * NN * ND;

    vq_prep_w<<<NF * NK * 8 / 256, 256, 0, stream>>>(w, wt, wh, wl, w2h);

    vq_argmin<<<NF * NN / 256, 256, 0, stream>>>(x_in, wh, wl, w2h, keys, flags);

    vq_rescue<<<NF * NN / 64 / 4, 256, 0, stream>>>(x_in, wt, w2h, flags, keys);

    vq_gather<<<NF * NN * 4 / 256, 256, 0, stream>>>(x_in, wt, keys, out, partial);

    vq_loss_final<<<1, 256, 0, stream>>>(partial, loss_slot);
}